// Round 1
// baseline (2148.986 us; speedup 1.0000x reference)
//
#include <hip/hip_runtime.h>
#include <math.h>

#define EPS 1e-5f

__device__ __forceinline__ float wred64(float v) {
#pragma unroll
    for (int off = 32; off > 0; off >>= 1) v += __shfl_down(v, off, 64);
    return v;
}

// ===================== channel LayerNorm (over axis=1, 256 ch) =====================
// grid (128, 8), block 256. Each block: 32 spatial positions of one batch.
__global__ __launch_bounds__(256) void chan_ln_kernel(
    const float* __restrict__ in, const float* __restrict__ w,
    const float* __restrict__ bias, float* __restrict__ out)
{
    __shared__ float tile[256 * 32];
    __shared__ float reds[8 * 32];
    __shared__ float redq[8 * 32];
    __shared__ float mus[32], rss[32];

    const int b = blockIdx.y;
    const int p0 = blockIdx.x * 32;
    const int q = threadIdx.x >> 5;   // 0..7 -> channel residue class
    const int p = threadIdx.x & 31;   // position within tile

    const float* src = in + (size_t)b * 256 * 4096 + p0 + p;
    float s = 0.f, s2 = 0.f;
#pragma unroll 8
    for (int j = 0; j < 32; ++j) {
        int c = j * 8 + q;
        float v = src[(size_t)c * 4096];
        tile[c * 32 + p] = v;
        s += v; s2 += v * v;
    }
    reds[q * 32 + p] = s;
    redq[q * 32 + p] = s2;
    __syncthreads();
    if (threadIdx.x < 32) {
        float ss = 0.f, qq = 0.f;
#pragma unroll
        for (int k = 0; k < 8; ++k) { ss += reds[k * 32 + threadIdx.x]; qq += redq[k * 32 + threadIdx.x]; }
        float mu = ss * (1.f / 256.f);
        float var = qq * (1.f / 256.f) - mu * mu;
        mus[threadIdx.x] = mu;
        rss[threadIdx.x] = rsqrtf(var + EPS);
    }
    __syncthreads();
    float mu = mus[p], rs = rss[p];
    float* dst = out + (size_t)b * 256 * 4096 + p0 + p;
#pragma unroll 8
    for (int j = 0; j < 32; ++j) {
        int c = j * 8 + q;
        float v = tile[c * 32 + p];
        dst[(size_t)c * 4096] = (v - mu) * rs * w[c] + bias[c];
    }
}

// ===================== fused attn_ema (+ residual) =====================
// grid (64, 8): blockIdx.x = Gi*8 + Hi, blockIdx.y = batch. block 1024.
// One block owns a (Gi,Hi) group: 4 channels x 64x64, fully in LDS (zero-padded 66x66).
__global__ __launch_bounds__(1024) void attn_kernel(
    const float* __restrict__ y, const float* __restrict__ x,
    const float* __restrict__ w1, const float* __restrict__ b1,
    const float* __restrict__ w3, const float* __restrict__ b3,
    const float* __restrict__ gn_w, const float* __restrict__ gn_b,
    float* __restrict__ out)
{
    __shared__ float gpad[4][66][66];
    __shared__ float xh_s[4][64];   // row sums (over w) per (c,h)
    __shared__ float xw_s[4][64];   // col sums (over h) per (c,w)
    __shared__ float sigh[4][64];
    __shared__ float sigw[4][64];
    __shared__ float wk[4][4][9];
    __shared__ float b3_s[4], gnw_s[4], gnb_s[4];
    __shared__ float st[12];        // [0..3]=sum(gate) [4..7]=sumsq(gate) [8..11]=sum(x2)
    __shared__ float mu_s[4], rs_s[4], a1_s[4], a2_s[4];

    const int b  = blockIdx.y;
    const int Gi = blockIdx.x >> 3;
    const int Hi = blockIdx.x & 7;
    const int c0 = Hi * 32 + Gi * 4;   // global channel base
    const int tid = threadIdx.x;
    const int lane = tid & 63, wav = tid >> 6;

    // ---- phase 0: zero pads/accumulators, load per-head params ----
    float* gl = &gpad[0][0][0];
    for (int i = tid; i < 4 * 66 * 66; i += 1024) gl[i] = 0.f;
    if (tid < 256) xw_s[tid >> 6][tid & 63] = 0.f;
    if (tid < 12) st[tid] = 0.f;
    if (tid < 144) (&wk[0][0][0])[tid] = w3[Hi * 144 + tid];
    if (tid < 4) {
        b3_s[tid]  = b3[Hi * 4 + tid];
        gnw_s[tid] = gn_w[Hi * 4 + tid];
        gnb_s[tid] = gn_b[Hi * 4 + tid];
    }
    __syncthreads();

    // ---- phase 1: load g interior ----
    {
        const float* src = y + ((size_t)(b * 256 + c0)) * 4096;
#pragma unroll
        for (int it = 0; it < 16; ++it) {
            int i = tid + it * 1024;
            int c = i >> 12, p = i & 4095;
            int h = p >> 6, ww = p & 63;
            gpad[c][h + 1][ww + 1] = src[(size_t)c * 4096 + p];
        }
    }
    __syncthreads();

    // ---- phase 2: row sums (wave shuffle) + col sums (LDS atomics) ----
    {
        float colp[4] = {0.f, 0.f, 0.f, 0.f};
#pragma unroll
        for (int c = 0; c < 4; ++c) {
#pragma unroll
            for (int rr = 0; rr < 4; ++rr) {
                int h = wav + rr * 16;
                float v = gpad[c][h + 1][lane + 1];
                colp[c] += v;
                float rsum = wred64(v);
                if (lane == 0) xh_s[c][h] = rsum;
            }
        }
#pragma unroll
        for (int c = 0; c < 4; ++c) atomicAdd(&xw_s[c][lane], colp[c]);
    }
    __syncthreads();

    // ---- phase 3: tiny 4x4 matmul + sigmoid -> sigh/sigw ----
    if (tid < 512) {
        int o = tid >> 7, s = tid & 127;
        float acc = b1[Hi * 4 + o];
#pragma unroll
        for (int i = 0; i < 4; ++i) {
            float cm = (s < 64 ? xh_s[i][s] : xw_s[i][s - 64]) * (1.f / 64.f);
            acc += w1[(Hi * 4 + o) * 4 + i] * cm;
        }
        float sg = 1.f / (1.f + expf(-acc));
        if (s < 64) sigh[o][s] = sg; else sigw[o][s - 64] = sg;
    }
    __syncthreads();

    // ---- phase 4: gate stats + grouped 3x3 conv (x2) + x2 sums ----
    float x2r[4][4];   // [pos][out-channel]
    {
        float s1[4] = {0.f,0.f,0.f,0.f}, sq[4] = {0.f,0.f,0.f,0.f};
#pragma unroll
        for (int pp = 0; pp < 4; ++pp)
#pragma unroll
            for (int o = 0; o < 4; ++o) x2r[pp][o] = b3_s[o];

#pragma unroll
        for (int pp = 0; pp < 4; ++pp) {
            int p = tid + pp * 1024;
            int h = p >> 6, ww = p & 63;
#pragma unroll
            for (int c = 0; c < 4; ++c) {
                float gate = gpad[c][h + 1][ww + 1] * sigh[c][h] * sigw[c][ww];
                s1[c] += gate; sq[c] += gate * gate;
            }
        }
#pragma unroll
        for (int i = 0; i < 4; ++i) {
            float wr[4][9];
#pragma unroll
            for (int o = 0; o < 4; ++o)
#pragma unroll
                for (int j = 0; j < 9; ++j) wr[o][j] = wk[o][i][j];
#pragma unroll
            for (int pp = 0; pp < 4; ++pp) {
                int p = tid + pp * 1024;
                int h = p >> 6, ww = p & 63;
                float v[9];
#pragma unroll
                for (int dy = 0; dy < 3; ++dy)
#pragma unroll
                    for (int dx = 0; dx < 3; ++dx)
                        v[dy * 3 + dx] = gpad[i][h + dy][ww + dx];
#pragma unroll
                for (int o = 0; o < 4; ++o) {
                    float a = 0.f;
#pragma unroll
                    for (int j = 0; j < 9; ++j) a += v[j] * wr[o][j];
                    x2r[pp][o] += a;
                }
            }
        }
        float sx2[4];
#pragma unroll
        for (int o = 0; o < 4; ++o)
            sx2[o] = x2r[0][o] + x2r[1][o] + x2r[2][o] + x2r[3][o];

#pragma unroll
        for (int c = 0; c < 4; ++c) {
            float r1 = wred64(s1[c]);
            float r2 = wred64(sq[c]);
            float r3 = wred64(sx2[c]);
            if (lane == 0) {
                atomicAdd(&st[c], r1);
                atomicAdd(&st[4 + c], r2);
                atomicAdd(&st[8 + c], r3);
            }
        }
    }
    __syncthreads();

    // ---- phase 5: finalize stats; a1 = softmax(gn_b) (exact), a2 = softmax(mean x2) ----
    if (tid == 0) {
        float m1 = -1e30f, m2 = -1e30f;
#pragma unroll
        for (int c = 0; c < 4; ++c) {
            float mu = st[c] * (1.f / 4096.f);
            float var = st[4 + c] * (1.f / 4096.f) - mu * mu;
            mu_s[c] = mu;
            rs_s[c] = rsqrtf(var + EPS);
            if (gnb_s[c] > m1) m1 = gnb_s[c];
            float mx = st[8 + c] * (1.f / 4096.f);
            if (mx > m2) m2 = mx;
        }
        float sum1 = 0.f, sum2 = 0.f, e1[4], e2[4];
#pragma unroll
        for (int c = 0; c < 4; ++c) {
            e1[c] = expf(gnb_s[c] - m1); sum1 += e1[c];
            e2[c] = expf(st[8 + c] * (1.f / 4096.f) - m2); sum2 += e2[c];
        }
#pragma unroll
        for (int c = 0; c < 4; ++c) {
            a1_s[c] = e1[c] / sum1;
            a2_s[c] = e2[c] / sum2;
        }
    }
    __syncthreads();

    // ---- phase 6: wmap, sigmoid, residual write ----
    {
        const size_t gbase = ((size_t)(b * 256 + c0)) * 4096;
#pragma unroll
        for (int pp = 0; pp < 4; ++pp) {
            int p = tid + pp * 1024;
            int h = p >> 6, ww = p & 63;
            float wm = 0.f;
#pragma unroll
            for (int c = 0; c < 4; ++c) {
                float gv = gpad[c][h + 1][ww + 1];
                float gate = gv * sigh[c][h] * sigw[c][ww];
                float x1v = (gate - mu_s[c]) * rs_s[c] * gnw_s[c] + gnb_s[c];
                wm += a1_s[c] * x2r[pp][c] + a2_s[c] * x1v;
            }
            float sg = 1.f / (1.f + expf(-wm));
#pragma unroll
            for (int c = 0; c < 4; ++c) {
                size_t idx = gbase + (size_t)c * 4096 + p;
                out[idx] = x[idx] + gpad[c][h + 1][ww + 1] * sg;
            }
        }
    }
}

// ===================== fp32 SGEMM: C[b] = A(MxK) * B[b](Kx4096) (+R) =====================
// grid (4096/128, ceil(M/128), nb), block 256, 8x8 microtile.
__global__ __launch_bounds__(256) void sgemm_kernel(
    const float* __restrict__ A, const float* __restrict__ Bg,
    const float* __restrict__ Rg, float* __restrict__ Cg,
    int M, int K, int resid)
{
    __shared__ float As[16][132];
    __shared__ float Bs[16][132];

    const int bz = blockIdx.z;
    const float* B = Bg + (size_t)bz * K * 4096;
    float* C = Cg + (size_t)bz * M * 4096;
    const float* R = Rg + (size_t)bz * M * 4096;

    const int m0 = blockIdx.y * 128;
    const int n0 = blockIdx.x * 128;
    const int tid = threadIdx.x;
    const int tx = tid & 15, ty = tid >> 4;
    const int ar = tid >> 2, aq = (tid & 3) * 4;
    const int br = tid >> 5, bq = (tid & 31) * 4;

    float acc[8][8];
#pragma unroll
    for (int i = 0; i < 8; ++i)
#pragma unroll
        for (int j = 0; j < 8; ++j) acc[i][j] = 0.f;

    const int ktiles = (K + 15) >> 4;
    for (int kt = 0; kt < ktiles; ++kt) {
        const int k0 = kt << 4;
#pragma unroll
        for (int half = 0; half < 2; ++half) {
            int row = ar + half * 64;
            int gm = m0 + row;
#pragma unroll
            for (int j = 0; j < 4; ++j) {
                int kk = aq + j;
                float v = 0.f;
                if (gm < M && (k0 + kk) < K) v = A[(size_t)gm * K + k0 + kk];
                As[kk][row] = v;
            }
        }
#pragma unroll
        for (int half = 0; half < 2; ++half) {
            int row = br + half * 8;
            int gk = k0 + row;
            float4 v = make_float4(0.f, 0.f, 0.f, 0.f);
            if (gk < K) v = *(const float4*)&B[(size_t)gk * 4096 + n0 + bq];
            *(float4*)&Bs[row][bq] = v;
        }
        __syncthreads();
#pragma unroll
        for (int kk = 0; kk < 16; ++kk) {
            float a[8], bb[8];
            *(float4*)&a[0]  = *(const float4*)&As[kk][ty * 8];
            *(float4*)&a[4]  = *(const float4*)&As[kk][ty * 8 + 4];
            *(float4*)&bb[0] = *(const float4*)&Bs[kk][tx * 8];
            *(float4*)&bb[4] = *(const float4*)&Bs[kk][tx * 8 + 4];
#pragma unroll
            for (int i = 0; i < 8; ++i)
#pragma unroll
                for (int j = 0; j < 8; ++j)
                    acc[i][j] += a[i] * bb[j];
        }
        __syncthreads();
    }
#pragma unroll
    for (int i = 0; i < 8; ++i) {
        int gm = m0 + ty * 8 + i;
        if (gm < M) {
            size_t base = (size_t)gm * 4096 + n0 + tx * 8;
            float4 o0, o1;
            o0.x = acc[i][0]; o0.y = acc[i][1]; o0.z = acc[i][2]; o0.w = acc[i][3];
            o1.x = acc[i][4]; o1.y = acc[i][5]; o1.z = acc[i][6]; o1.w = acc[i][7];
            if (resid) {
                float4 r0 = *(const float4*)&R[base];
                float4 r1 = *(const float4*)&R[base + 4];
                o0.x += r0.x; o0.y += r0.y; o0.z += r0.z; o0.w += r0.w;
                o1.x += r1.x; o1.y += r1.y; o1.z += r1.z; o1.w += r1.w;
            }
            *(float4*)&C[base] = o0;
            *(float4*)&C[base + 4] = o1;
        }
    }
}

// ===================== depthwise 3x3 conv + exact GELU gating =====================
// grid (680, 4, nb), block 256. t[c] = gelu(dw(z[c])) * dw(z[c+680])
__global__ __launch_bounds__(256) void dwgelu_kernel(
    const float* __restrict__ Zg, const float* __restrict__ wdw,
    float* __restrict__ Tg)
{
    __shared__ float zt[2][18][66];
    const int bz = blockIdx.z;
    const int c  = blockIdx.x;        // 0..679
    const int r0 = blockIdx.y * 16;
    const float* Z = Zg + (size_t)bz * 1360 * 4096;
    float* T = Tg + (size_t)bz * 680 * 4096;
    const int tid = threadIdx.x;

#pragma unroll
    for (int sel = 0; sel < 2; ++sel) {
        const float* src = Z + (size_t)(c + sel * 680) * 4096;
        for (int i = tid; i < 18 * 66; i += 256) {
            int rr = i / 66, cc = i % 66;
            int h = r0 - 1 + rr, w = cc - 1;
            float v = 0.f;
            if (h >= 0 && h < 64 && w >= 0 && w < 64) v = src[h * 64 + w];
            zt[sel][rr][cc] = v;
        }
    }
    __syncthreads();
    float w1r[9], w2r[9];
#pragma unroll
    for (int j = 0; j < 9; ++j) {
        w1r[j] = wdw[c * 9 + j];
        w2r[j] = wdw[(c + 680) * 9 + j];
    }
#pragma unroll
    for (int i = 0; i < 4; ++i) {
        int p = tid + i * 256;
        int hl = p >> 6, w = p & 63;
        float d1 = 0.f, d2 = 0.f;
#pragma unroll
        for (int dy = 0; dy < 3; ++dy)
#pragma unroll
            for (int dx = 0; dx < 3; ++dx) {
                d1 += zt[0][hl + dy][w + dx] * w1r[dy * 3 + dx];
                d2 += zt[1][hl + dy][w + dx] * w2r[dy * 3 + dx];
            }
        float g = 0.5f * d1 * (1.f + erff(d1 * 0.70710678118654752f));
        T[(size_t)c * 4096 + (r0 + hl) * 64 + w] = g * d2;
    }
}

// ===================== host =====================
extern "C" void kernel_launch(void* const* d_in, const int* in_sizes, int n_in,
                              void* d_out, int out_size, void* d_ws, size_t ws_size,
                              hipStream_t stream)
{
    const float* x     = (const float*)d_in[0];
    const float* ln1w  = (const float*)d_in[1];
    const float* ln1b  = (const float*)d_in[2];
    const float* w1    = (const float*)d_in[3];
    const float* b1    = (const float*)d_in[4];
    const float* w3    = (const float*)d_in[5];
    const float* b3    = (const float*)d_in[6];
    const float* gnw   = (const float*)d_in[7];
    const float* gnb   = (const float*)d_in[8];
    const float* ln2w  = (const float*)d_in[9];
    const float* ln2b  = (const float*)d_in[10];
    const float* w_in  = (const float*)d_in[11];
    const float* w_dw  = (const float*)d_in[12];
    const float* w_out = (const float*)d_in[13];
    float* out = (float*)d_out;

    char* ws = (char*)d_ws;
    const size_t SZ_X = (size_t)8 * 256 * 4096 * 4;    // 33.55 MB
    const size_t Z1   = (size_t)1360 * 4096 * 4;       // per-batch z: 22.28 MB
    const size_t T1   = (size_t)680 * 4096 * 4;        // per-batch t: 11.14 MB

    float* y    = (float*)(ws);
    float* out1 = (float*)(ws + SZ_X);
    float* zbuf = (float*)(ws + 2 * SZ_X);

    const size_t need_full = 2 * SZ_X + 8 * (Z1 + T1);
    const bool full = (ws_size >= need_full);

    // LN1: x -> y
    chan_ln_kernel<<<dim3(128, 8), dim3(256), 0, stream>>>(x, ln1w, ln1b, y);
    // attn (+residual): out1 = x + attn(y)
    attn_kernel<<<dim3(64, 8), dim3(1024), 0, stream>>>(y, x, w1, b1, w3, b3, gnw, gnb, out1);
    // LN2: out1 -> y (reuse)
    chan_ln_kernel<<<dim3(128, 8), dim3(256), 0, stream>>>(out1, ln2w, ln2b, y);

    if (full) {
        float* tbuf = (float*)(ws + 2 * SZ_X + 8 * Z1);
        sgemm_kernel<<<dim3(32, 11, 8), dim3(256), 0, stream>>>(w_in, y, zbuf, zbuf, 1360, 256, 0);
        dwgelu_kernel<<<dim3(680, 4, 8), dim3(256), 0, stream>>>(zbuf, w_dw, tbuf);
        sgemm_kernel<<<dim3(32, 2, 8), dim3(256), 0, stream>>>(w_out, tbuf, out1, out, 256, 680, 1);
    } else {
        float* tbuf = (float*)(ws + 2 * SZ_X + Z1);
        for (int b = 0; b < 8; ++b) {
            const float* yb = y + (size_t)b * 256 * 4096;
            const float* rb = out1 + (size_t)b * 256 * 4096;
            float* ob = out + (size_t)b * 256 * 4096;
            sgemm_kernel<<<dim3(32, 11, 1), dim3(256), 0, stream>>>(w_in, yb, zbuf, zbuf, 1360, 256, 0);
            dwgelu_kernel<<<dim3(680, 4, 1), dim3(256), 0, stream>>>(zbuf, w_dw, tbuf);
            sgemm_kernel<<<dim3(32, 2, 1), dim3(256), 0, stream>>>(w_out, tbuf, rb, ob, 256, 680, 1);
        }
    }
}

// Round 2
// 976.966 us; speedup vs baseline: 2.1997x; 2.1997x over previous
//
#include <hip/hip_runtime.h>
#include <math.h>

#define EPS 1e-5f

typedef unsigned short u16;
typedef __attribute__((ext_vector_type(8))) short bf16x8;
typedef __attribute__((ext_vector_type(4))) float f32x4;

__device__ __forceinline__ u16 f2bf(float f) {
    unsigned u = __builtin_bit_cast(unsigned, f);
    u += 0x7FFFu + ((u >> 16) & 1u);
    return (u16)(u >> 16);
}
__device__ __forceinline__ float bf2f(u16 h) {
    return __builtin_bit_cast(float, (unsigned)h << 16);
}
__device__ __forceinline__ float wred64(float v) {
#pragma unroll
    for (int off = 32; off > 0; off >>= 1) v += __shfl_down(v, off, 64);
    return v;
}

// ===================== weight prep: fp32 -> bf16 (+ dw-weight transpose) =====================
__global__ __launch_bounds__(256) void prep_kernel(
    const float* __restrict__ w_in, const float* __restrict__ w_out, const float* __restrict__ wdw,
    u16* __restrict__ wib, u16* __restrict__ wob, float* __restrict__ wdwT)
{
    int i = blockIdx.x * 256 + threadIdx.x;
    if (i < 1360 * 256) wib[i] = f2bf(w_in[i]);
    if (i < 256 * 680)  wob[i] = f2bf(w_out[i]);
    if (i < 1360 * 9) { int c = i / 9, j = i % 9; wdwT[j * 1360 + c] = wdw[i]; }
}

// ===================== LN1 stats only (mu, rsqrt per position) =====================
__global__ __launch_bounds__(256) void ln_stats_kernel(const float* __restrict__ x,
    float* __restrict__ mu_g, float* __restrict__ rs_g)
{
    __shared__ float r1[4][64], r2[4][64];
    const int b = blockIdx.y, p0 = blockIdx.x * 64;
    const int t = threadIdx.x, p = t & 63, q = t >> 6;
    const float* src = x + (size_t)b * 256 * 4096 + (size_t)q * 64 * 4096 + p0 + p;
    float s = 0.f, s2 = 0.f;
#pragma unroll 8
    for (int j = 0; j < 64; ++j) { float v = src[(size_t)j * 4096]; s += v; s2 += v * v; }
    r1[q][p] = s; r2[q][p] = s2;
    __syncthreads();
    if (t < 64) {
        float ss = r1[0][t] + r1[1][t] + r1[2][t] + r1[3][t];
        float qq = r2[0][t] + r2[1][t] + r2[2][t] + r2[3][t];
        float mu = ss * (1.f / 256.f);
        float var = qq * (1.f / 256.f) - mu * mu;
        mu_g[(size_t)b * 4096 + p0 + t] = mu;
        rs_g[(size_t)b * 4096 + p0 + t] = rsqrtf(var + EPS);
    }
}

// ===================== fused LN1-apply + attn_ema + residual =====================
// grid (64, 8): blockIdx.x = Gi*8 + Hi. block 1024. Spill-free restructure of phase 4.
__global__ __launch_bounds__(1024, 4) void attn_kernel(
    const float* __restrict__ x, const float* __restrict__ mu_g, const float* __restrict__ rs_g,
    const float* __restrict__ ln1w, const float* __restrict__ ln1b,
    const float* __restrict__ w1, const float* __restrict__ b1,
    const float* __restrict__ w3, const float* __restrict__ b3,
    const float* __restrict__ gn_w, const float* __restrict__ gn_b,
    float* __restrict__ out)
{
    __shared__ float gpad[4][66][66];
    __shared__ float xh_s[4][64], xw_s[4][64], sigh[4][64], sigw[4][64];
    __shared__ float wk[4][4][9];
    __shared__ float st[12];
    __shared__ float b3_s[4], gnw_s[4], gnb_s[4], lw_s[4], lb_s[4];
    __shared__ float mu_s[4], rs_s[4], a1_s[4], a2_s[4];

    const int b  = blockIdx.y;
    const int Gi = blockIdx.x >> 3;
    const int Hi = blockIdx.x & 7;
    const int c0 = Hi * 32 + Gi * 4;
    const int tid = threadIdx.x;
    const int lane = tid & 63, wav = tid >> 6;

    // phase 0: zero pad, load per-head params
    float* gl = &gpad[0][0][0];
    for (int i = tid; i < 4 * 66 * 66; i += 1024) gl[i] = 0.f;
    if (tid < 256) xw_s[tid >> 6][tid & 63] = 0.f;
    if (tid < 12) st[tid] = 0.f;
    if (tid < 144) (&wk[0][0][0])[tid] = w3[Hi * 144 + tid];
    if (tid < 4) {
        b3_s[tid]  = b3[Hi * 4 + tid];
        gnw_s[tid] = gn_w[Hi * 4 + tid];
        gnb_s[tid] = gn_b[Hi * 4 + tid];
        lw_s[tid]  = ln1w[c0 + tid];
        lb_s[tid]  = ln1b[c0 + tid];
    }
    __syncthreads();

    // phase 1: load x, apply LN1 on the fly
    {
        const float* src = x + ((size_t)(b * 256 + c0)) * 4096;
        const float* mug = mu_g + (size_t)b * 4096;
        const float* rsg = rs_g + (size_t)b * 4096;
#pragma unroll
        for (int it = 0; it < 16; ++it) {
            const int c = it >> 2;
            const int p = tid + (it & 3) * 1024;
            const int h = p >> 6, ww = p & 63;
            float v = src[(size_t)c * 4096 + p];
            gpad[c][h + 1][ww + 1] = (v - mug[p]) * rsg[p] * lw_s[c] + lb_s[c];
        }
    }
    __syncthreads();

    // phase 2: row sums + col sums
    {
        float colp[4] = {0.f, 0.f, 0.f, 0.f};
#pragma unroll
        for (int c = 0; c < 4; ++c) {
#pragma unroll
            for (int rr = 0; rr < 4; ++rr) {
                int h = wav + rr * 16;
                float v = gpad[c][h + 1][lane + 1];
                colp[c] += v;
                float rsum = wred64(v);
                if (lane == 0) xh_s[c][h] = rsum;
            }
        }
#pragma unroll
        for (int c = 0; c < 4; ++c) atomicAdd(&xw_s[c][lane], colp[c]);
    }
    __syncthreads();

    // phase 3: 4x4 matmul + sigmoid
    if (tid < 512) {
        int o = tid >> 7, s = tid & 127;
        float acc = b1[Hi * 4 + o];
#pragma unroll
        for (int i = 0; i < 4; ++i) {
            float cm = (s < 64 ? xh_s[i][s] : xw_s[i][s - 64]) * (1.f / 64.f);
            acc += w1[(Hi * 4 + o) * 4 + i] * cm;
        }
        float sg = 1.f / (1.f + expf(-acc));
        if (s < 64) sigh[o][s] = sg; else sigw[o][s - 64] = sg;
    }
    __syncthreads();

    // phase 4a: gate stats
    float x2r[4][4];
    {
        float s1[4] = {0.f,0.f,0.f,0.f}, sq[4] = {0.f,0.f,0.f,0.f};
#pragma unroll
        for (int pp = 0; pp < 4; ++pp) {
            const int p = tid + pp * 1024, h = p >> 6, w = p & 63;
#pragma unroll
            for (int c = 0; c < 4; ++c) {
                float gate = gpad[c][h + 1][w + 1] * sigh[c][h] * sigw[c][w];
                s1[c] += gate; sq[c] += gate * gate;
            }
        }
#pragma unroll
        for (int c = 0; c < 4; ++c) {
            float r1v = wred64(s1[c]);
            float r2v = wred64(sq[c]);
            if (lane == 0) { atomicAdd(&st[c], r1v); atomicAdd(&st[4 + c], r2v); }
        }
    }
    // phase 4b: grouped 3x3 conv, o-chunked weights (spill-free)
#pragma unroll
    for (int pp = 0; pp < 4; ++pp)
#pragma unroll
        for (int o = 0; o < 4; ++o) x2r[pp][o] = b3_s[o];
#pragma unroll
    for (int i = 0; i < 4; ++i) {
#pragma unroll
        for (int oc = 0; oc < 2; ++oc) {
            float w2[2][9];
#pragma unroll
            for (int o2 = 0; o2 < 2; ++o2)
#pragma unroll
                for (int j = 0; j < 9; ++j) w2[o2][j] = wk[oc * 2 + o2][i][j];
#pragma unroll
            for (int pp = 0; pp < 4; ++pp) {
                const int p = tid + pp * 1024, h = p >> 6, w = p & 63;
                float v[9];
#pragma unroll
                for (int dy = 0; dy < 3; ++dy)
#pragma unroll
                    for (int dx = 0; dx < 3; ++dx) v[dy * 3 + dx] = gpad[i][h + dy][w + dx];
#pragma unroll
                for (int o2 = 0; o2 < 2; ++o2) {
                    float a = 0.f;
#pragma unroll
                    for (int j = 0; j < 9; ++j) a += v[j] * w2[o2][j];
                    x2r[pp][oc * 2 + o2] += a;
                }
            }
        }
    }
#pragma unroll
    for (int o = 0; o < 4; ++o) {
        float sx = x2r[0][o] + x2r[1][o] + x2r[2][o] + x2r[3][o];
        float r3v = wred64(sx);
        if (lane == 0) atomicAdd(&st[8 + o], r3v);
    }
    __syncthreads();

    // phase 5: stats finalize; a1 = softmax(gn_b) exactly; a2 = softmax(mean x2)
    if (tid == 0) {
        float m1 = -1e30f, m2 = -1e30f;
#pragma unroll
        for (int c = 0; c < 4; ++c) {
            float mu = st[c] * (1.f / 4096.f);
            float var = st[4 + c] * (1.f / 4096.f) - mu * mu;
            mu_s[c] = mu;
            rs_s[c] = rsqrtf(var + EPS);
            if (gnb_s[c] > m1) m1 = gnb_s[c];
            float mx = st[8 + c] * (1.f / 4096.f);
            if (mx > m2) m2 = mx;
        }
        float sum1 = 0.f, sum2 = 0.f, e1[4], e2[4];
#pragma unroll
        for (int c = 0; c < 4; ++c) {
            e1[c] = expf(gnb_s[c] - m1); sum1 += e1[c];
            e2[c] = expf(st[8 + c] * (1.f / 4096.f) - m2); sum2 += e2[c];
        }
#pragma unroll
        for (int c = 0; c < 4; ++c) { a1_s[c] = e1[c] / sum1; a2_s[c] = e2[c] / sum2; }
    }
    __syncthreads();

    // phase 6: wmap + sigmoid + residual
    {
        const size_t gbase = ((size_t)(b * 256 + c0)) * 4096;
#pragma unroll
        for (int pp = 0; pp < 4; ++pp) {
            const int p = tid + pp * 1024, h = p >> 6, w = p & 63;
            float wm = 0.f;
#pragma unroll
            for (int c = 0; c < 4; ++c) {
                float gv = gpad[c][h + 1][w + 1];
                float gate = gv * sigh[c][h] * sigw[c][w];
                float x1v = (gate - mu_s[c]) * rs_s[c] * gnw_s[c] + gnb_s[c];
                wm += a1_s[c] * x2r[pp][c] + a2_s[c] * x1v;
            }
            float sg = 1.f / (1.f + expf(-wm));
#pragma unroll
            for (int c = 0; c < 4; ++c) {
                size_t idx = gbase + (size_t)c * 4096 + p;
                out[idx] = x[idx] + gpad[c][h + 1][w + 1] * sg;
            }
        }
    }
}

// ===================== LN2 with transposed bf16 output y2T[b][p][256] =====================
__global__ __launch_bounds__(256) void ln2T_kernel(const float* __restrict__ in,
    const float* __restrict__ w, const float* __restrict__ bias, u16* __restrict__ outT)
{
    __shared__ float tile[256][33];
    __shared__ float reds[8][32], redq[8][32];
    __shared__ float mus[32], rss[32];
    __shared__ float ws_[256], bs_[256];

    const int b = blockIdx.y, p0 = blockIdx.x * 32;
    const int t = threadIdx.x, q = t >> 5, p = t & 31;
    ws_[t] = w[t]; bs_[t] = bias[t];

    const float* src = in + (size_t)b * 256 * 4096 + p0 + p;
    float s = 0.f, s2 = 0.f;
#pragma unroll 8
    for (int j = 0; j < 32; ++j) {
        int c = j * 8 + q;
        float v = src[(size_t)c * 4096];
        tile[c][p] = v; s += v; s2 += v * v;
    }
    reds[q][p] = s; redq[q][p] = s2;
    __syncthreads();
    if (t < 32) {
        float ss = 0.f, qq = 0.f;
#pragma unroll
        for (int k = 0; k < 8; ++k) { ss += reds[k][t]; qq += redq[k][t]; }
        float mu = ss * (1.f / 256.f);
        float var = qq * (1.f / 256.f) - mu * mu;
        mus[t] = mu; rss[t] = rsqrtf(var + EPS);
    }
    __syncthreads();
    const int pr = t >> 3, ch = t & 7;
    const float muv = mus[pr], rsv = rss[pr];
    unsigned pk[16];
#pragma unroll
    for (int jj = 0; jj < 16; ++jj) {
        int c = ch * 32 + jj * 2;
        float v0 = (tile[c][pr] - muv) * rsv * ws_[c] + bs_[c];
        float v1 = (tile[c + 1][pr] - muv) * rsv * ws_[c + 1] + bs_[c + 1];
        pk[jj] = (unsigned)f2bf(v0) | ((unsigned)f2bf(v1) << 16);
    }
    u16* dst = outT + ((size_t)b * 4096 + p0 + pr) * 256 + ch * 32;
#pragma unroll
    for (int k = 0; k < 4; ++k) {
        uint4 ov; ov.x = pk[k*4]; ov.y = pk[k*4+1]; ov.z = pk[k*4+2]; ov.w = pk[k*4+3];
        ((uint4*)dst)[k] = ov;
    }
}

// ===================== MFMA GEMM1: zT[p][1360] = (w_in[1360][256] . y2T^T) transposed =====================
// grid (32, 11, nb), block 256 (4 waves 2x2), 128x128 tile, BK=64.
__global__ __launch_bounds__(256, 4) void gemm1_kernel(
    const u16* __restrict__ Abf, const u16* __restrict__ Bt, u16* __restrict__ Zt)
{
    union SMEM { struct { u16 A[128][72]; u16 B[128][72]; } ab; u16 T[128][136]; };
    __shared__ SMEM sm;
    const int bz = blockIdx.z;
    const int n0 = blockIdx.x * 128, m0 = blockIdx.y * 128;
    const int tid = threadIdx.x;
    const int l = tid & 63, wv = tid >> 6, wr = wv >> 1, wc = wv & 1;
    const int lr = l & 15, lg = l >> 4;
    const int srow = tid >> 1, shalf = tid & 1;

    f32x4 acc[4][4];
    const f32x4 fzero = {0.f, 0.f, 0.f, 0.f};
#pragma unroll
    for (int i = 0; i < 4; ++i)
#pragma unroll
        for (int j = 0; j < 4; ++j) acc[i][j] = fzero;

    const u16* gA = Abf + (size_t)(m0 + srow) * 256 + shalf * 32;
    const u16* gB = Bt + ((size_t)bz * 4096 + n0 + srow) * 256 + shalf * 32;
    const bool aok = (m0 + srow) < 1360;
    const uint4 z4 = {0u, 0u, 0u, 0u};

#pragma unroll 1
    for (int kt = 0; kt < 4; ++kt) {
        uint4 av[4], bv[4];
#pragma unroll
        for (int i = 0; i < 4; ++i) {
            av[i] = aok ? ((const uint4*)(gA + kt * 64))[i] : z4;
            bv[i] = ((const uint4*)(gB + kt * 64))[i];
        }
        __syncthreads();
#pragma unroll
        for (int i = 0; i < 4; ++i) {
            ((uint4*)&sm.ab.A[srow][shalf * 32])[i] = av[i];
            ((uint4*)&sm.ab.B[srow][shalf * 32])[i] = bv[i];
        }
        __syncthreads();
#pragma unroll
        for (int kc = 0; kc < 2; ++kc) {
            bf16x8 af[4], bfr[4];
#pragma unroll
            for (int mf = 0; mf < 4; ++mf)
                af[mf] = *(const bf16x8*)&sm.ab.A[wr * 64 + mf * 16 + lr][kc * 32 + lg * 8];
#pragma unroll
            for (int nf = 0; nf < 4; ++nf)
                bfr[nf] = *(const bf16x8*)&sm.ab.B[wc * 64 + nf * 16 + lr][kc * 32 + lg * 8];
#pragma unroll
            for (int mf = 0; mf < 4; ++mf)
#pragma unroll
                for (int nf = 0; nf < 4; ++nf)
                    acc[mf][nf] = __builtin_amdgcn_mfma_f32_16x16x32_bf16(af[mf], bfr[nf], acc[mf][nf], 0, 0, 0);
        }
    }
    // epilogue: transpose 128x128 via LDS, emit bf16 zT[p][m]
    __syncthreads();
#pragma unroll
    for (int mf = 0; mf < 4; ++mf)
#pragma unroll
        for (int nf = 0; nf < 4; ++nf) {
            int ml = wr * 64 + mf * 16 + lg * 4;
            int nl = wc * 64 + nf * 16 + lr;
            f32x4 c = acc[mf][nf];
            unsigned q0 = (unsigned)f2bf(c.x) | ((unsigned)f2bf(c.y) << 16);
            unsigned q1 = (unsigned)f2bf(c.z) | ((unsigned)f2bf(c.w) << 16);
            *(uint2*)&sm.T[nl][ml] = make_uint2(q0, q1);
        }
    __syncthreads();
    {
        size_t zrow = ((size_t)bz * 4096 + n0 + srow) * 1360 + m0 + shalf * 64;
#pragma unroll
        for (int k = 0; k < 8; ++k) {
            int mch = m0 + shalf * 64 + k * 8;
            if (mch + 8 <= 1360)
                *(uint4*)&Zt[zrow + k * 8] = ((const uint4*)&sm.T[srow][shalf * 64])[k];
        }
    }
}

// ===================== N-major depthwise 3x3 + exact GELU gating: tT[p][680] =====================
// grid (256, nb): blockIdx.x -> (h, c-quarter) with XCD swizzle. No LDS; L1 absorbs halo.
__device__ __forceinline__ void fma8(float (&acc)[8], uint4 zv, float4 w0, float4 w1) {
    acc[0] += bf2f((u16)(zv.x & 0xFFFFu)) * w0.x;
    acc[1] += bf2f((u16)(zv.x >> 16))     * w0.y;
    acc[2] += bf2f((u16)(zv.y & 0xFFFFu)) * w0.z;
    acc[3] += bf2f((u16)(zv.y >> 16))     * w0.w;
    acc[4] += bf2f((u16)(zv.z & 0xFFFFu)) * w1.x;
    acc[5] += bf2f((u16)(zv.z >> 16))     * w1.y;
    acc[6] += bf2f((u16)(zv.w & 0xFFFFu)) * w1.z;
    acc[7] += bf2f((u16)(zv.w >> 16))     * w1.w;
}

__global__ __launch_bounds__(256) void dwgeluT_kernel(
    const u16* __restrict__ zT, const float* __restrict__ wdwT, u16* __restrict__ tT)
{
    const int bz = blockIdx.y;
    const int ib = (blockIdx.x & 7) * 32 + (blockIdx.x >> 3);   // XCD-contiguous h-bands
    const int h = ib >> 2, cq = ib & 3;
    const int t = threadIdx.x, w = t & 63, cvq = t >> 6;
    const int s = cq * 4 + cvq;
    const bool rok0 = h > 0, rok2 = h < 63;
    const bool cok0 = w > 0, cok2 = w < 63;
    const u16* zb = zT + ((size_t)bz * 4096 + (size_t)h * 64 + w) * 1360;
    u16* tb = tT + ((size_t)bz * 4096 + (size_t)h * 64 + w) * 680;
    const uint4 z4 = {0u, 0u, 0u, 0u};

    for (int cv = s; cv < 85; cv += 16) {
        const int c8 = cv * 8;
        float a1[8], a2[8];
#pragma unroll
        for (int k = 0; k < 8; ++k) { a1[k] = 0.f; a2[k] = 0.f; }
#pragma unroll
        for (int dy = 0; dy < 3; ++dy) {
            const bool rok = (dy == 0) ? rok0 : (dy == 2 ? rok2 : true);
            const u16* rp = zb + ((long)dy - 1) * 64 * 1360;
#pragma unroll
            for (int dx = 0; dx < 3; ++dx) {
                const bool ok = rok && ((dx == 0) ? cok0 : (dx == 2 ? cok2 : true));
                const u16* p1 = rp + ((long)dx - 1) * 1360 + c8;
                const int j = dy * 3 + dx;
                uint4 zv1 = ok ? *(const uint4*)p1 : z4;
                uint4 zv2 = ok ? *(const uint4*)(p1 + 680) : z4;
                const float* wp = wdwT + j * 1360 + c8;
                float4 wa0 = *(const float4*)wp;
                float4 wa1 = *(const float4*)(wp + 4);
                float4 wb0 = *(const float4*)(wp + 680);
                float4 wb1 = *(const float4*)(wp + 684);
                fma8(a1, zv1, wa0, wa1);
                fma8(a2, zv2, wb0, wb1);
            }
        }
        unsigned pk[4];
#pragma unroll
        for (int k = 0; k < 4; ++k) {
            float d0 = a1[k * 2], d1 = a1[k * 2 + 1];
            float g0 = 0.5f * d0 * (1.f + erff(d0 * 0.70710678118654752f)) * a2[k * 2];
            float g1 = 0.5f * d1 * (1.f + erff(d1 * 0.70710678118654752f)) * a2[k * 2 + 1];
            pk[k] = (unsigned)f2bf(g0) | ((unsigned)f2bf(g1) << 16);
        }
        uint4 ov; ov.x = pk[0]; ov.y = pk[1]; ov.z = pk[2]; ov.w = pk[3];
        *(uint4*)(tb + c8) = ov;
    }
}

// ===================== MFMA GEMM2: out[b][256][4096] = w_out . t + out (residual RMW) =====================
// grid (32, 2, 8), block 256, 128x128 tile, BK=64, K=680 with tail guards.
__global__ __launch_bounds__(256, 4) void gemm2_kernel(
    const u16* __restrict__ Abf, const u16* __restrict__ Bt, float* __restrict__ out)
{
    __shared__ u16 As[128][72];
    __shared__ u16 Bs[128][72];
    const int bz = blockIdx.z;
    const int n0 = blockIdx.x * 128, m0 = blockIdx.y * 128;
    const int tid = threadIdx.x;
    const int l = tid & 63, wv = tid >> 6, wr = wv >> 1, wc = wv & 1;
    const int lr = l & 15, lg = l >> 4;
    const int srow = tid >> 1, shalf = tid & 1;

    f32x4 acc[4][4];
    const f32x4 fzero = {0.f, 0.f, 0.f, 0.f};
#pragma unroll
    for (int i = 0; i < 4; ++i)
#pragma unroll
        for (int j = 0; j < 4; ++j) acc[i][j] = fzero;

    const u16* gA = Abf + (size_t)(m0 + srow) * 680;
    const u16* gB = Bt + ((size_t)bz * 4096 + n0 + srow) * 680;
    const uint4 z4 = {0u, 0u, 0u, 0u};

#pragma unroll 1
    for (int kt = 0; kt < 11; ++kt) {
        const int k0 = kt * 64 + shalf * 32;
        uint4 av[4], bv[4];
#pragma unroll
        for (int i = 0; i < 4; ++i) {
            int kk = k0 + i * 8;
            bool ok = (kk + 8) <= 680;
            av[i] = ok ? *(const uint4*)(gA + kk) : z4;
            bv[i] = ok ? *(const uint4*)(gB + kk) : z4;
        }
        __syncthreads();
#pragma unroll
        for (int i = 0; i < 4; ++i) {
            ((uint4*)&As[srow][shalf * 32])[i] = av[i];
            ((uint4*)&Bs[srow][shalf * 32])[i] = bv[i];
        }
        __syncthreads();
#pragma unroll
        for (int kc = 0; kc < 2; ++kc) {
            bf16x8 af[4], bfr[4];
#pragma unroll
            for (int mf = 0; mf < 4; ++mf)
                af[mf] = *(const bf16x8*)&As[wr * 64 + mf * 16 + lr][kc * 32 + lg * 8];
#pragma unroll
            for (int nf = 0; nf < 4; ++nf)
                bfr[nf] = *(const bf16x8*)&Bs[wc * 64 + nf * 16 + lr][kc * 32 + lg * 8];
#pragma unroll
            for (int mf = 0; mf < 4; ++mf)
#pragma unroll
                for (int nf = 0; nf < 4; ++nf)
                    acc[mf][nf] = __builtin_amdgcn_mfma_f32_16x16x32_bf16(af[mf], bfr[nf], acc[mf][nf], 0, 0, 0);
        }
    }
    // epilogue: direct c-major store with fused residual
#pragma unroll
    for (int mf = 0; mf < 4; ++mf)
#pragma unroll
        for (int nf = 0; nf < 4; ++nf) {
            int m = m0 + wr * 64 + mf * 16 + lg * 4;
            int n = n0 + wc * 64 + nf * 16 + lr;
            size_t base = ((size_t)bz * 256 + m) * 4096 + n;
            f32x4 c = acc[mf][nf];
#pragma unroll
            for (int r = 0; r < 4; ++r) {
                size_t idx = base + (size_t)r * 4096;
                out[idx] = out[idx] + c[r];
            }
        }
}

// ===================== host =====================
extern "C" void kernel_launch(void* const* d_in, const int* in_sizes, int n_in,
                              void* d_out, int out_size, void* d_ws, size_t ws_size,
                              hipStream_t stream)
{
    const float* x     = (const float*)d_in[0];
    const float* ln1w  = (const float*)d_in[1];
    const float* ln1b  = (const float*)d_in[2];
    const float* w1    = (const float*)d_in[3];
    const float* b1    = (const float*)d_in[4];
    const float* w3    = (const float*)d_in[5];
    const float* b3    = (const float*)d_in[6];
    const float* gnw   = (const float*)d_in[7];
    const float* gnb   = (const float*)d_in[8];
    const float* ln2w  = (const float*)d_in[9];
    const float* ln2b  = (const float*)d_in[10];
    const float* w_in  = (const float*)d_in[11];
    const float* w_dw  = (const float*)d_in[12];
    const float* w_out = (const float*)d_in[13];
    float* out = (float*)d_out;

    char* ws = (char*)d_ws;
    float* mu_g = (float*)(ws + 0);            // 131072
    float* rs_g = (float*)(ws + 131072);       // 131072
    u16*   y2T  = (u16*)(ws + 262144);         // 16,777,216
    u16*   tT   = (u16*)(ws + 17039360);       // 44,564,480
    u16*   wib  = (u16*)(ws + 61603840);       // 696,320
    u16*   wob  = (u16*)(ws + 62300160);       // 348,160
    float* wdwT = (float*)(ws + 62648320);     // 48,960 (padded to 49,152)
    u16*   zT   = (u16*)(ws + 62697472);       // full: 89,128,960 ; mid: 11,141,120
    const bool full = ws_size >= (62697472ull + 89128960ull);

    prep_kernel<<<dim3(1360), dim3(256), 0, stream>>>(w_in, w_out, w_dw, wib, wob, wdwT);
    ln_stats_kernel<<<dim3(64, 8), dim3(256), 0, stream>>>(x, mu_g, rs_g);
    attn_kernel<<<dim3(64, 8), dim3(1024), 0, stream>>>(x, mu_g, rs_g, ln1w, ln1b,
                                                        w1, b1, w3, b3, gnw, gnb, out);
    ln2T_kernel<<<dim3(128, 8), dim3(256), 0, stream>>>(out, ln2w, ln2b, y2T);

    if (full) {
        gemm1_kernel<<<dim3(32, 11, 8), dim3(256), 0, stream>>>(wib, y2T, zT);
        dwgeluT_kernel<<<dim3(256, 8), dim3(256), 0, stream>>>(zT, wdwT, tT);
    } else {
        for (int b = 0; b < 8; ++b) {
            gemm1_kernel<<<dim3(32, 11, 1), dim3(256), 0, stream>>>(
                wib, y2T + (size_t)b * 4096 * 256, zT);
            dwgeluT_kernel<<<dim3(256, 1), dim3(256), 0, stream>>>(
                zT, wdwT, tT + (size_t)b * 4096 * 680);
        }
    }
    gemm2_kernel<<<dim3(32, 2, 8), dim3(256), 0, stream>>>(wob, tT, out);
}

// Round 3
// 678.145 us; speedup vs baseline: 3.1689x; 1.4406x over previous
//
#include <hip/hip_runtime.h>
#include <math.h>

#define EPS 1e-5f

typedef unsigned short u16;
typedef __attribute__((ext_vector_type(8))) short bf16x8;
typedef __attribute__((ext_vector_type(4))) float f32x4;

__device__ __forceinline__ u16 f2bf(float f) {
    unsigned u = __builtin_bit_cast(unsigned, f);
    u += 0x7FFFu + ((u >> 16) & 1u);
    return (u16)(u >> 16);
}
__device__ __forceinline__ float bf2f(u16 h) {
    return __builtin_bit_cast(float, (unsigned)h << 16);
}
__device__ __forceinline__ float wred64(float v) {
#pragma unroll
    for (int off = 32; off > 0; off >>= 1) v += __shfl_down(v, off, 64);
    return v;
}

// ===================== weight prep: fp32 -> bf16 =====================
__global__ __launch_bounds__(256) void prep_kernel(
    const float* __restrict__ w_in, const float* __restrict__ w_out,
    u16* __restrict__ wib, u16* __restrict__ wob)
{
    int i = blockIdx.x * 256 + threadIdx.x;
    if (i < 1360 * 256) wib[i] = f2bf(w_in[i]);
    if (i < 256 * 680)  wob[i] = f2bf(w_out[i]);
}

// ===================== LN1 stats only (mu, rsqrt per position) =====================
__global__ __launch_bounds__(256) void ln_stats_kernel(const float* __restrict__ x,
    float* __restrict__ mu_g, float* __restrict__ rs_g)
{
    __shared__ float r1[4][64], r2[4][64];
    const int b = blockIdx.y, p0 = blockIdx.x * 64;
    const int t = threadIdx.x, p = t & 63, q = t >> 6;
    const float* src = x + (size_t)b * 256 * 4096 + (size_t)q * 64 * 4096 + p0 + p;
    float s = 0.f, s2 = 0.f;
#pragma unroll 8
    for (int j = 0; j < 64; ++j) { float v = src[(size_t)j * 4096]; s += v; s2 += v * v; }
    r1[q][p] = s; r2[q][p] = s2;
    __syncthreads();
    if (t < 64) {
        float ss = r1[0][t] + r1[1][t] + r1[2][t] + r1[3][t];
        float qq = r2[0][t] + r2[1][t] + r2[2][t] + r2[3][t];
        float mu = ss * (1.f / 256.f);
        float var = qq * (1.f / 256.f) - mu * mu;
        mu_g[(size_t)b * 4096 + p0 + t] = mu;
        rs_g[(size_t)b * 4096 + p0 + t] = rsqrtf(var + EPS);
    }
}

// ===================== fused LN1-apply + attn_ema + residual =====================
__global__ __launch_bounds__(1024, 4) void attn_kernel(
    const float* __restrict__ x, const float* __restrict__ mu_g, const float* __restrict__ rs_g,
    const float* __restrict__ ln1w, const float* __restrict__ ln1b,
    const float* __restrict__ w1, const float* __restrict__ b1,
    const float* __restrict__ w3, const float* __restrict__ b3,
    const float* __restrict__ gn_w, const float* __restrict__ gn_b,
    float* __restrict__ out)
{
    __shared__ float gpad[4][66][66];
    __shared__ float xh_s[4][64], xw_s[4][64], sigh[4][64], sigw[4][64];
    __shared__ float wk[4][4][9];
    __shared__ float st[12];
    __shared__ float b3_s[4], gnw_s[4], gnb_s[4], lw_s[4], lb_s[4];
    __shared__ float mu_s[4], rs_s[4], a1_s[4], a2_s[4];

    const int b  = blockIdx.y;
    const int Gi = blockIdx.x >> 3;
    const int Hi = blockIdx.x & 7;
    const int c0 = Hi * 32 + Gi * 4;
    const int tid = threadIdx.x;
    const int lane = tid & 63, wav = tid >> 6;

    float* gl = &gpad[0][0][0];
    for (int i = tid; i < 4 * 66 * 66; i += 1024) gl[i] = 0.f;
    if (tid < 256) xw_s[tid >> 6][tid & 63] = 0.f;
    if (tid < 12) st[tid] = 0.f;
    if (tid < 144) (&wk[0][0][0])[tid] = w3[Hi * 144 + tid];
    if (tid < 4) {
        b3_s[tid]  = b3[Hi * 4 + tid];
        gnw_s[tid] = gn_w[Hi * 4 + tid];
        gnb_s[tid] = gn_b[Hi * 4 + tid];
        lw_s[tid]  = ln1w[c0 + tid];
        lb_s[tid]  = ln1b[c0 + tid];
    }
    __syncthreads();

    {
        const float* src = x + ((size_t)(b * 256 + c0)) * 4096;
        const float* mug = mu_g + (size_t)b * 4096;
        const float* rsg = rs_g + (size_t)b * 4096;
#pragma unroll
        for (int it = 0; it < 16; ++it) {
            const int c = it >> 2;
            const int p = tid + (it & 3) * 1024;
            const int h = p >> 6, ww = p & 63;
            float v = src[(size_t)c * 4096 + p];
            gpad[c][h + 1][ww + 1] = (v - mug[p]) * rsg[p] * lw_s[c] + lb_s[c];
        }
    }
    __syncthreads();

    {
        float colp[4] = {0.f, 0.f, 0.f, 0.f};
#pragma unroll
        for (int c = 0; c < 4; ++c) {
#pragma unroll
            for (int rr = 0; rr < 4; ++rr) {
                int h = wav + rr * 16;
                float v = gpad[c][h + 1][lane + 1];
                colp[c] += v;
                float rsum = wred64(v);
                if (lane == 0) xh_s[c][h] = rsum;
            }
        }
#pragma unroll
        for (int c = 0; c < 4; ++c) atomicAdd(&xw_s[c][lane], colp[c]);
    }
    __syncthreads();

    if (tid < 512) {
        int o = tid >> 7, s = tid & 127;
        float acc = b1[Hi * 4 + o];
#pragma unroll
        for (int i = 0; i < 4; ++i) {
            float cm = (s < 64 ? xh_s[i][s] : xw_s[i][s - 64]) * (1.f / 64.f);
            acc += w1[(Hi * 4 + o) * 4 + i] * cm;
        }
        float sg = 1.f / (1.f + expf(-acc));
        if (s < 64) sigh[o][s] = sg; else sigw[o][s - 64] = sg;
    }
    __syncthreads();

    float x2r[4][4];
    {
        float s1[4] = {0.f,0.f,0.f,0.f}, sq[4] = {0.f,0.f,0.f,0.f};
#pragma unroll
        for (int pp = 0; pp < 4; ++pp) {
            const int p = tid + pp * 1024, h = p >> 6, w = p & 63;
#pragma unroll
            for (int c = 0; c < 4; ++c) {
                float gate = gpad[c][h + 1][w + 1] * sigh[c][h] * sigw[c][w];
                s1[c] += gate; sq[c] += gate * gate;
            }
        }
#pragma unroll
        for (int c = 0; c < 4; ++c) {
            float r1v = wred64(s1[c]);
            float r2v = wred64(sq[c]);
            if (lane == 0) { atomicAdd(&st[c], r1v); atomicAdd(&st[4 + c], r2v); }
        }
    }
#pragma unroll
    for (int pp = 0; pp < 4; ++pp)
#pragma unroll
        for (int o = 0; o < 4; ++o) x2r[pp][o] = b3_s[o];
#pragma unroll
    for (int i = 0; i < 4; ++i) {
#pragma unroll
        for (int oc = 0; oc < 2; ++oc) {
            float w2[2][9];
#pragma unroll
            for (int o2 = 0; o2 < 2; ++o2)
#pragma unroll
                for (int j = 0; j < 9; ++j) w2[o2][j] = wk[oc * 2 + o2][i][j];
#pragma unroll
            for (int pp = 0; pp < 4; ++pp) {
                const int p = tid + pp * 1024, h = p >> 6, w = p & 63;
                float v[9];
#pragma unroll
                for (int dy = 0; dy < 3; ++dy)
#pragma unroll
                    for (int dx = 0; dx < 3; ++dx) v[dy * 3 + dx] = gpad[i][h + dy][w + dx];
#pragma unroll
                for (int o2 = 0; o2 < 2; ++o2) {
                    float a = 0.f;
#pragma unroll
                    for (int j = 0; j < 9; ++j) a += v[j] * w2[o2][j];
                    x2r[pp][oc * 2 + o2] += a;
                }
            }
        }
    }
#pragma unroll
    for (int o = 0; o < 4; ++o) {
        float sx = x2r[0][o] + x2r[1][o] + x2r[2][o] + x2r[3][o];
        float r3v = wred64(sx);
        if (lane == 0) atomicAdd(&st[8 + o], r3v);
    }
    __syncthreads();

    if (tid == 0) {
        float m1 = -1e30f, m2 = -1e30f;
#pragma unroll
        for (int c = 0; c < 4; ++c) {
            float mu = st[c] * (1.f / 4096.f);
            float var = st[4 + c] * (1.f / 4096.f) - mu * mu;
            mu_s[c] = mu;
            rs_s[c] = rsqrtf(var + EPS);
            if (gnb_s[c] > m1) m1 = gnb_s[c];
            float mx = st[8 + c] * (1.f / 4096.f);
            if (mx > m2) m2 = mx;
        }
        float sum1 = 0.f, sum2 = 0.f, e1[4], e2[4];
#pragma unroll
        for (int c = 0; c < 4; ++c) {
            e1[c] = expf(gnb_s[c] - m1); sum1 += e1[c];
            e2[c] = expf(st[8 + c] * (1.f / 4096.f) - m2); sum2 += e2[c];
        }
#pragma unroll
        for (int c = 0; c < 4; ++c) { a1_s[c] = e1[c] / sum1; a2_s[c] = e2[c] / sum2; }
    }
    __syncthreads();

    {
        const size_t gbase = ((size_t)(b * 256 + c0)) * 4096;
#pragma unroll
        for (int pp = 0; pp < 4; ++pp) {
            const int p = tid + pp * 1024, h = p >> 6, w = p & 63;
            float wm = 0.f;
#pragma unroll
            for (int c = 0; c < 4; ++c) {
                float gv = gpad[c][h + 1][w + 1];
                float gate = gv * sigh[c][h] * sigw[c][w];
                float x1v = (gate - mu_s[c]) * rs_s[c] * gnw_s[c] + gnb_s[c];
                wm += a1_s[c] * x2r[pp][c] + a2_s[c] * x1v;
            }
            float sg = 1.f / (1.f + expf(-wm));
#pragma unroll
            for (int c = 0; c < 4; ++c) {
                size_t idx = gbase + (size_t)c * 4096 + p;
                out[idx] = x[idx] + gpad[c][h + 1][w + 1] * sg;
            }
        }
    }
}

// ===================== LN2 with transposed bf16 output y2T[b][p][256] =====================
__global__ __launch_bounds__(256) void ln2T_kernel(const float* __restrict__ in,
    const float* __restrict__ w, const float* __restrict__ bias, u16* __restrict__ outT)
{
    __shared__ float tile[256][33];
    __shared__ float reds[8][32], redq[8][32];
    __shared__ float mus[32], rss[32];
    __shared__ float ws_[256], bs_[256];

    const int b = blockIdx.y, p0 = blockIdx.x * 32;
    const int t = threadIdx.x, q = t >> 5, p = t & 31;
    ws_[t] = w[t]; bs_[t] = bias[t];

    const float* src = in + (size_t)b * 256 * 4096 + p0 + p;
    float s = 0.f, s2 = 0.f;
#pragma unroll 8
    for (int j = 0; j < 32; ++j) {
        int c = j * 8 + q;
        float v = src[(size_t)c * 4096];
        tile[c][p] = v; s += v; s2 += v * v;
    }
    reds[q][p] = s; redq[q][p] = s2;
    __syncthreads();
    if (t < 32) {
        float ss = 0.f, qq = 0.f;
#pragma unroll
        for (int k = 0; k < 8; ++k) { ss += reds[k][t]; qq += redq[k][t]; }
        float mu = ss * (1.f / 256.f);
        float var = qq * (1.f / 256.f) - mu * mu;
        mus[t] = mu; rss[t] = rsqrtf(var + EPS);
    }
    __syncthreads();
    const int pr = t >> 3, ch = t & 7;
    const float muv = mus[pr], rsv = rss[pr];
    unsigned pk[16];
#pragma unroll
    for (int jj = 0; jj < 16; ++jj) {
        int c = ch * 32 + jj * 2;
        float v0 = (tile[c][pr] - muv) * rsv * ws_[c] + bs_[c];
        float v1 = (tile[c + 1][pr] - muv) * rsv * ws_[c + 1] + bs_[c + 1];
        pk[jj] = (unsigned)f2bf(v0) | ((unsigned)f2bf(v1) << 16);
    }
    u16* dst = outT + ((size_t)b * 4096 + p0 + pr) * 256 + ch * 32;
#pragma unroll
    for (int k = 0; k < 4; ++k) {
        uint4 ov; ov.x = pk[k*4]; ov.y = pk[k*4+1]; ov.z = pk[k*4+2]; ov.w = pk[k*4+3];
        ((uint4*)dst)[k] = ov;
    }
}

// ===================== MFMA GEMM1: z[b][1360][4096] (c-major) = w_in . y2T^T =====================
// grid (32, 11, nb), block 256 (4 waves 2x2), 128x128 tile, BK=64.
__global__ __launch_bounds__(256, 3) void gemm1_kernel(
    const u16* __restrict__ Abf, const u16* __restrict__ Bt, u16* __restrict__ Z)
{
    union SMEM { struct { u16 A[128][72]; u16 B[128][72]; } ab; u16 T[128][136]; };
    __shared__ SMEM sm;
    const int bz = blockIdx.z;
    const int n0 = blockIdx.x * 128, m0 = blockIdx.y * 128;
    const int tid = threadIdx.x;
    const int l = tid & 63, wv = tid >> 6, wr = wv >> 1, wc = wv & 1;
    const int lr = l & 15, lg = l >> 4;
    const int srow = tid >> 1, shalf = tid & 1;

    f32x4 acc[4][4];
    const f32x4 fzero = {0.f, 0.f, 0.f, 0.f};
#pragma unroll
    for (int i = 0; i < 4; ++i)
#pragma unroll
        for (int j = 0; j < 4; ++j) acc[i][j] = fzero;

    const u16* gA = Abf + (size_t)(m0 + srow) * 256 + shalf * 32;
    const u16* gB = Bt + ((size_t)bz * 4096 + n0 + srow) * 256 + shalf * 32;
    const bool aok = (m0 + srow) < 1360;
    const uint4 z4 = {0u, 0u, 0u, 0u};

#pragma unroll 1
    for (int kt = 0; kt < 4; ++kt) {
        uint4 av[4], bv[4];
#pragma unroll
        for (int i = 0; i < 4; ++i) {
            av[i] = aok ? ((const uint4*)(gA + kt * 64))[i] : z4;
            bv[i] = ((const uint4*)(gB + kt * 64))[i];
        }
        __syncthreads();
#pragma unroll
        for (int i = 0; i < 4; ++i) {
            ((uint4*)&sm.ab.A[srow][shalf * 32])[i] = av[i];
            ((uint4*)&sm.ab.B[srow][shalf * 32])[i] = bv[i];
        }
        __syncthreads();
#pragma unroll
        for (int kc = 0; kc < 2; ++kc) {
            bf16x8 af[4], bfr[4];
#pragma unroll
            for (int mf = 0; mf < 4; ++mf)
                af[mf] = *(const bf16x8*)&sm.ab.A[wr * 64 + mf * 16 + lr][kc * 32 + lg * 8];
#pragma unroll
            for (int nf = 0; nf < 4; ++nf)
                bfr[nf] = *(const bf16x8*)&sm.ab.B[wc * 64 + nf * 16 + lr][kc * 32 + lg * 8];
#pragma unroll
            for (int mf = 0; mf < 4; ++mf)
#pragma unroll
                for (int nf = 0; nf < 4; ++nf)
                    acc[mf][nf] = __builtin_amdgcn_mfma_f32_16x16x32_bf16(af[mf], bfr[nf], acc[mf][nf], 0, 0, 0);
        }
    }
    // epilogue: stage [m][n] bf16 tile, linear coalesced store (c-major)
    __syncthreads();
#pragma unroll
    for (int mf = 0; mf < 4; ++mf)
#pragma unroll
        for (int nf = 0; nf < 4; ++nf) {
            int ml = wr * 64 + mf * 16 + lg * 4;
            int nl = wc * 64 + nf * 16 + lr;
            f32x4 c = acc[mf][nf];
            sm.T[ml + 0][nl] = f2bf(c.x);
            sm.T[ml + 1][nl] = f2bf(c.y);
            sm.T[ml + 2][nl] = f2bf(c.z);
            sm.T[ml + 3][nl] = f2bf(c.w);
        }
    __syncthreads();
    {
        const int gm = m0 + srow;
        if (gm < 1360) {
            u16* drow = Z + (size_t)bz * 1360 * 4096 + (size_t)gm * 4096 + n0 + shalf * 64;
#pragma unroll
            for (int k = 0; k < 8; ++k)
                ((uint4*)drow)[k] = ((const uint4*)&sm.T[srow][shalf * 64])[k];
        }
    }
}

// ===================== spatial-major depthwise 3x3 + exact GELU: t[b][680][4096] =====================
// grid (680, 4, nb), block 256. LDS-staged 18x66 tile per plane, 4-wide strips per thread.
__global__ __launch_bounds__(256) void dwgelu_kernel(
    const u16* __restrict__ z, const float* __restrict__ wdw, u16* __restrict__ t)
{
    __shared__ u16 zt[2][18][66];
    const int bz = blockIdx.z;
    const int c  = blockIdx.x;        // 0..679
    const int r0 = blockIdx.y * 16;
    const int tid = threadIdx.x;
    const u16* Z = z + (size_t)bz * 1360 * 4096;

#pragma unroll
    for (int sel = 0; sel < 2; ++sel) {
        const u16* src = Z + (size_t)(c + sel * 680) * 4096;
        for (int i = tid; i < 18 * 66; i += 256) {
            int rr = i / 66, cc = i % 66;
            int h = r0 - 1 + rr, w = cc - 1;
            u16 v = 0;
            if (h >= 0 && h < 64 && w >= 0 && w < 64) v = src[h * 64 + w];
            zt[sel][rr][cc] = v;
        }
    }
    __syncthreads();

    float w1r[9], w2r[9];
#pragma unroll
    for (int j = 0; j < 9; ++j) {
        w1r[j] = wdw[c * 9 + j];
        w2r[j] = wdw[(c + 680) * 9 + j];
    }
    const int hl = tid >> 4;          // 0..15
    const int w0 = (tid & 15) * 4;    // 0..60

    float d1a[4] = {0.f, 0.f, 0.f, 0.f}, d2a[4] = {0.f, 0.f, 0.f, 0.f};
#pragma unroll
    for (int dy = 0; dy < 3; ++dy) {
        float r1[6], r2[6];
#pragma unroll
        for (int k = 0; k < 6; ++k) {
            r1[k] = bf2f(zt[0][hl + dy][w0 + k]);
            r2[k] = bf2f(zt[1][hl + dy][w0 + k]);
        }
#pragma unroll
        for (int p = 0; p < 4; ++p) {
            d1a[p] += r1[p] * w1r[dy * 3] + r1[p + 1] * w1r[dy * 3 + 1] + r1[p + 2] * w1r[dy * 3 + 2];
            d2a[p] += r2[p] * w2r[dy * 3] + r2[p + 1] * w2r[dy * 3 + 1] + r2[p + 2] * w2r[dy * 3 + 2];
        }
    }
    unsigned pk[2];
#pragma unroll
    for (int k = 0; k < 2; ++k) {
        float da = d1a[k * 2], db = d1a[k * 2 + 1];
        float g0 = 0.5f * da * (1.f + erff(da * 0.70710678118654752f)) * d2a[k * 2];
        float g1 = 0.5f * db * (1.f + erff(db * 0.70710678118654752f)) * d2a[k * 2 + 1];
        pk[k] = (unsigned)f2bf(g0) | ((unsigned)f2bf(g1) << 16);
    }
    u16* dst = t + (size_t)bz * 680 * 4096 + (size_t)c * 4096 + (r0 + hl) * 64 + w0;
    *(uint2*)dst = make_uint2(pk[0], pk[1]);
}

// ===================== LDS-tiled transpose: t[b][680][4096] -> tT[b][4096][680] =====================
// grid (64, 11, nb), block 256.
__global__ __launch_bounds__(256) void transpose_kernel(
    const u16* __restrict__ t, u16* __restrict__ tT)
{
    __shared__ u16 tile[64][68];
    const int bz = blockIdx.z;
    const int p0 = blockIdx.x * 64;
    const int c0 = blockIdx.y * 64;
    const int tid = threadIdx.x;
    const u16* src = t + (size_t)bz * 680 * 4096;
    u16* dst = tT + (size_t)bz * 4096 * 680;

#pragma unroll
    for (int it = 0; it < 4; ++it) {
        int i = tid + it * 256;
        int r = i >> 4, cc = (i & 15) * 4;
        uint2 v = make_uint2(0u, 0u);
        if (c0 + r < 680) v = *(const uint2*)&src[(size_t)(c0 + r) * 4096 + p0 + cc];
        *(uint2*)&tile[r][cc] = v;
    }
    __syncthreads();
#pragma unroll
    for (int it = 0; it < 4; ++it) {
        int i = tid + it * 256;
        int pp = i >> 4, cc = (i & 15) * 4;
        if (c0 + cc < 680) {
            u16 a = tile[cc][pp], b = tile[cc + 1][pp];
            u16 c = tile[cc + 2][pp], d = tile[cc + 3][pp];
            uint2 v;
            v.x = (unsigned)a | ((unsigned)b << 16);
            v.y = (unsigned)c | ((unsigned)d << 16);
            *(uint2*)&dst[(size_t)(p0 + pp) * 680 + c0 + cc] = v;
        }
    }
}

// ===================== MFMA GEMM2: out[b][256][4096] += w_out . t =====================
// grid (32, 2, nb), block 256, 128x128 tile, BK=64, K=680 with tail guards.
__global__ __launch_bounds__(256, 3) void gemm2_kernel(
    const u16* __restrict__ Abf, const u16* __restrict__ Bt, float* __restrict__ out)
{
    __shared__ u16 As[128][72];
    __shared__ u16 Bs[128][72];
    const int bz = blockIdx.z;
    const int n0 = blockIdx.x * 128, m0 = blockIdx.y * 128;
    const int tid = threadIdx.x;
    const int l = tid & 63, wv = tid >> 6, wr = wv >> 1, wc = wv & 1;
    const int lr = l & 15, lg = l >> 4;
    const int srow = tid >> 1, shalf = tid & 1;

    f32x4 acc[4][4];
    const f32x4 fzero = {0.f, 0.f, 0.f, 0.f};
#pragma unroll
    for (int i = 0; i < 4; ++i)
#pragma unroll
        for (int j = 0; j < 4; ++j) acc[i][j] = fzero;

    const u16* gA = Abf + (size_t)(m0 + srow) * 680;
    const u16* gB = Bt + ((size_t)bz * 4096 + n0 + srow) * 680;
    const uint4 z4 = {0u, 0u, 0u, 0u};

#pragma unroll 1
    for (int kt = 0; kt < 11; ++kt) {
        const int k0 = kt * 64 + shalf * 32;
        uint4 av[4], bv[4];
#pragma unroll
        for (int i = 0; i < 4; ++i) {
            int kk = k0 + i * 8;
            bool ok = (kk + 8) <= 680;
            av[i] = ok ? *(const uint4*)(gA + kk) : z4;
            bv[i] = ok ? *(const uint4*)(gB + kk) : z4;
        }
        __syncthreads();
#pragma unroll
        for (int i = 0; i < 4; ++i) {
            ((uint4*)&As[srow][shalf * 32])[i] = av[i];
            ((uint4*)&Bs[srow][shalf * 32])[i] = bv[i];
        }
        __syncthreads();
#pragma unroll
        for (int kc = 0; kc < 2; ++kc) {
            bf16x8 af[4], bfr[4];
#pragma unroll
            for (int mf = 0; mf < 4; ++mf)
                af[mf] = *(const bf16x8*)&As[wr * 64 + mf * 16 + lr][kc * 32 + lg * 8];
#pragma unroll
            for (int nf = 0; nf < 4; ++nf)
                bfr[nf] = *(const bf16x8*)&Bs[wc * 64 + nf * 16 + lr][kc * 32 + lg * 8];
#pragma unroll
            for (int mf = 0; mf < 4; ++mf)
#pragma unroll
                for (int nf = 0; nf < 4; ++nf)
                    acc[mf][nf] = __builtin_amdgcn_mfma_f32_16x16x32_bf16(af[mf], bfr[nf], acc[mf][nf], 0, 0, 0);
        }
    }
#pragma unroll
    for (int mf = 0; mf < 4; ++mf)
#pragma unroll
        for (int nf = 0; nf < 4; ++nf) {
            int m = m0 + wr * 64 + mf * 16 + lg * 4;
            int n = n0 + wc * 64 + nf * 16 + lr;
            size_t base = ((size_t)bz * 256 + m) * 4096 + n;
            f32x4 c = acc[mf][nf];
#pragma unroll
            for (int r = 0; r < 4; ++r) {
                size_t idx = base + (size_t)r * 4096;
                out[idx] = out[idx] + c[r];
            }
        }
}

// ===================== host =====================
extern "C" void kernel_launch(void* const* d_in, const int* in_sizes, int n_in,
                              void* d_out, int out_size, void* d_ws, size_t ws_size,
                              hipStream_t stream)
{
    const float* x     = (const float*)d_in[0];
    const float* ln1w  = (const float*)d_in[1];
    const float* ln1b  = (const float*)d_in[2];
    const float* w1    = (const float*)d_in[3];
    const float* b1    = (const float*)d_in[4];
    const float* w3    = (const float*)d_in[5];
    const float* b3    = (const float*)d_in[6];
    const float* gnw   = (const float*)d_in[7];
    const float* gnb   = (const float*)d_in[8];
    const float* ln2w  = (const float*)d_in[9];
    const float* ln2b  = (const float*)d_in[10];
    const float* w_in  = (const float*)d_in[11];
    const float* w_dw  = (const float*)d_in[12];
    const float* w_out = (const float*)d_in[13];
    float* out = (float*)d_out;

    char* ws = (char*)d_ws;
    // layout
    const size_t OFF_RS  = 131072;
    const size_t OFF_Y2T = 262144;
    const size_t OFF_WIB = 17039360;       // y2T end: 262144 + 16777216
    const size_t OFF_WOB = 17735680;       // wib end
    const size_t OFF_Z   = 18087936;       // wob end 18083840, pad
    const size_t Z_FULL  = 89128960;       // 8*1360*4096*2
    const size_t OFF_T   = OFF_Z + Z_FULL; // 107216896
    const size_t T_FULL  = 44564480;       // 8*680*4096*2
    const size_t NEED_FULL = OFF_T + T_FULL; // 151781376

    float* mu_g = (float*)(ws);
    float* rs_g = (float*)(ws + OFF_RS);
    u16*   y2T  = (u16*)(ws + OFF_Y2T);
    u16*   wib  = (u16*)(ws + OFF_WIB);
    u16*   wob  = (u16*)(ws + OFF_WOB);
    const bool full = ws_size >= NEED_FULL;

    prep_kernel<<<dim3(1360), dim3(256), 0, stream>>>(w_in, w_out, wib, wob);
    ln_stats_kernel<<<dim3(64, 8), dim3(256), 0, stream>>>(x, mu_g, rs_g);
    attn_kernel<<<dim3(64, 8), dim3(1024), 0, stream>>>(x, mu_g, rs_g, ln1w, ln1b,
                                                        w1, b1, w3, b3, gnw, gnb, out);
    ln2T_kernel<<<dim3(128, 8), dim3(256), 0, stream>>>(out, ln2w, ln2b, y2T);

    if (full) {
        u16* z   = (u16*)(ws + OFF_Z);
        u16* t   = (u16*)(ws + OFF_T);
        u16* tT  = (u16*)(ws + OFF_Z);     // overlays z (dead after dwgelu)
        gemm1_kernel<<<dim3(32, 11, 8), dim3(256), 0, stream>>>(wib, y2T, z);
        dwgelu_kernel<<<dim3(680, 4, 8), dim3(256), 0, stream>>>(z, w_dw, t);
        transpose_kernel<<<dim3(64, 11, 8), dim3(256), 0, stream>>>(t, tT);
        gemm2_kernel<<<dim3(32, 2, 8), dim3(256), 0, stream>>>(wob, tT, out);
    } else {
        const size_t Z1 = (size_t)1360 * 4096 * 2;   // 11141120
        const size_t T1 = (size_t)680 * 4096 * 2;    // 5570560
        u16* z  = (u16*)(ws + OFF_Z);
        u16* t  = (u16*)(ws + OFF_Z + Z1);
        u16* tT = (u16*)(ws + OFF_Z + Z1 + T1);
        for (int b = 0; b < 8; ++b) {
            gemm1_kernel<<<dim3(32, 11, 1), dim3(256), 0, stream>>>(
                wib, y2T + (size_t)b * 4096 * 256, z);
            dwgelu_kernel<<<dim3(680, 4, 1), dim3(256), 0, stream>>>(z, w_dw, t);
            transpose_kernel<<<dim3(64, 11, 1), dim3(256), 0, stream>>>(t, tT);
            gemm2_kernel<<<dim3(32, 2, 1), dim3(256), 0, stream>>>(
                wob, tT, out + (size_t)b * 256 * 4096);
        }
    }
}

// Round 5
// 516.968 us; speedup vs baseline: 4.1569x; 1.3118x over previous
//
#include <hip/hip_runtime.h>
#include <math.h>

#define EPS 1e-5f

typedef unsigned short u16;
typedef __attribute__((ext_vector_type(8))) short bf16x8;
typedef __attribute__((ext_vector_type(4))) float f32x4;

__device__ __forceinline__ u16 f2bf(float f) {
    unsigned u = __builtin_bit_cast(unsigned, f);
    u += 0x7FFFu + ((u >> 16) & 1u);
    return (u16)(u >> 16);
}
__device__ __forceinline__ float bf2f(u16 h) {
    return __builtin_bit_cast(float, (unsigned)h << 16);
}
__device__ __forceinline__ float wred64(float v) {
#pragma unroll
    for (int off = 32; off > 0; off >>= 1) v += __shfl_down(v, off, 64);
    return v;
}

// ===================== weight prep: fp32 -> bf16 =====================
__global__ __launch_bounds__(256) void prep_kernel(
    const float* __restrict__ w_in, const float* __restrict__ w_out,
    u16* __restrict__ wib, u16* __restrict__ wob)
{
    int i = blockIdx.x * 256 + threadIdx.x;
    if (i < 1360 * 256) wib[i] = f2bf(w_in[i]);
    if (i < 256 * 680)  wob[i] = f2bf(w_out[i]);
}

// ===================== LN1 stats only (mu, rsqrt per position) =====================
__global__ __launch_bounds__(256) void ln_stats_kernel(const float* __restrict__ x,
    float* __restrict__ mu_g, float* __restrict__ rs_g)
{
    __shared__ float r1[4][64], r2[4][64];
    const int b = blockIdx.y, p0 = blockIdx.x * 64;
    const int t = threadIdx.x, p = t & 63, q = t >> 6;
    const float* src = x + (size_t)b * 256 * 4096 + (size_t)q * 64 * 4096 + p0 + p;
    float s = 0.f, s2 = 0.f;
#pragma unroll 8
    for (int j = 0; j < 64; ++j) { float v = src[(size_t)j * 4096]; s += v; s2 += v * v; }
    r1[q][p] = s; r2[q][p] = s2;
    __syncthreads();
    if (t < 64) {
        float ss = r1[0][t] + r1[1][t] + r1[2][t] + r1[3][t];
        float qq = r2[0][t] + r2[1][t] + r2[2][t] + r2[3][t];
        float mu = ss * (1.f / 256.f);
        float var = qq * (1.f / 256.f) - mu * mu;
        mu_g[(size_t)b * 4096 + p0 + t] = mu;
        rs_g[(size_t)b * 4096 + p0 + t] = rsqrtf(var + EPS);
    }
}

// ===================== fused LN1-apply + attn_ema + residual =====================
// LDS ~140KB -> 1 block/CU -> compiler targets 4 waves/SIMD -> 128 VGPR cap, no spills.
// x2 (group conv result) lives in LDS; thread-owned positions, race-free without barriers.
__global__ __launch_bounds__(1024, 4) void attn_kernel(
    const float* __restrict__ x, const float* __restrict__ mu_g, const float* __restrict__ rs_g,
    const float* __restrict__ ln1w, const float* __restrict__ ln1b,
    const float* __restrict__ w1, const float* __restrict__ b1,
    const float* __restrict__ w3, const float* __restrict__ b3,
    const float* __restrict__ gn_w, const float* __restrict__ gn_b,
    float* __restrict__ out)
{
    __shared__ float gpad[4][66][66];     // 69,696 B
    __shared__ float x2_lds[4][4096];     // 65,536 B
    __shared__ float xh_s[4][64], xw_s[4][64], sigh[4][64], sigw[4][64];
    __shared__ float wk[4][4][9];
    __shared__ float st[12];
    __shared__ float b3_s[4], gnw_s[4], gnb_s[4], lw_s[4], lb_s[4];
    __shared__ float mu_s[4], rs_s[4], a1_s[4], a2_s[4];

    const int b  = blockIdx.y;
    const int Gi = blockIdx.x >> 3;
    const int Hi = blockIdx.x & 7;
    const int c0 = Hi * 32 + Gi * 4;
    const int tid = threadIdx.x;
    const int lane = tid & 63, wav = tid >> 6;

    // phase 0: zero pad, load per-head params
    float* gl = &gpad[0][0][0];
    for (int i = tid; i < 4 * 66 * 66; i += 1024) gl[i] = 0.f;
    if (tid < 256) xw_s[tid >> 6][tid & 63] = 0.f;
    if (tid < 12) st[tid] = 0.f;
    if (tid < 144) (&wk[0][0][0])[tid] = w3[Hi * 144 + tid];
    if (tid < 4) {
        b3_s[tid]  = b3[Hi * 4 + tid];
        gnw_s[tid] = gn_w[Hi * 4 + tid];
        gnb_s[tid] = gn_b[Hi * 4 + tid];
        lw_s[tid]  = ln1w[c0 + tid];
        lb_s[tid]  = ln1b[c0 + tid];
    }
    __syncthreads();

    // phase 1: load x, apply LN1 on the fly
    {
        const float* src = x + ((size_t)(b * 256 + c0)) * 4096;
        const float* mug = mu_g + (size_t)b * 4096;
        const float* rsg = rs_g + (size_t)b * 4096;
#pragma unroll
        for (int it = 0; it < 16; ++it) {
            const int c = it >> 2;
            const int p = tid + (it & 3) * 1024;
            const int h = p >> 6, ww = p & 63;
            float v = src[(size_t)c * 4096 + p];
            gpad[c][h + 1][ww + 1] = (v - mug[p]) * rsg[p] * lw_s[c] + lb_s[c];
        }
    }
    __syncthreads();

    // phase 2: row sums + col sums
    {
        float colp[4] = {0.f, 0.f, 0.f, 0.f};
#pragma unroll
        for (int c = 0; c < 4; ++c) {
#pragma unroll
            for (int rr = 0; rr < 4; ++rr) {
                int h = wav + rr * 16;
                float v = gpad[c][h + 1][lane + 1];
                colp[c] += v;
                float rsum = wred64(v);
                if (lane == 0) xh_s[c][h] = rsum;
            }
        }
#pragma unroll
        for (int c = 0; c < 4; ++c) atomicAdd(&xw_s[c][lane], colp[c]);
    }
    __syncthreads();

    // phase 3: 4x4 matmul + sigmoid
    if (tid < 512) {
        int o = tid >> 7, s = tid & 127;
        float acc = b1[Hi * 4 + o];
#pragma unroll
        for (int i = 0; i < 4; ++i) {
            float cm = (s < 64 ? xh_s[i][s] : xw_s[i][s - 64]) * (1.f / 64.f);
            acc += w1[(Hi * 4 + o) * 4 + i] * cm;
        }
        float sg = 1.f / (1.f + expf(-acc));
        if (s < 64) sigh[o][s] = sg; else sigw[o][s - 64] = sg;
    }
    __syncthreads();

    // phase 4a: gate stats
    {
        float s1[4] = {0.f,0.f,0.f,0.f}, sq[4] = {0.f,0.f,0.f,0.f};
#pragma unroll
        for (int pp = 0; pp < 4; ++pp) {
            const int p = tid + pp * 1024, h = p >> 6, w = p & 63;
#pragma unroll
            for (int c = 0; c < 4; ++c) {
                float gate = gpad[c][h + 1][w + 1] * sigh[c][h] * sigw[c][w];
                s1[c] += gate; sq[c] += gate * gate;
            }
        }
#pragma unroll
        for (int c = 0; c < 4; ++c) {
            float r1v = wred64(s1[c]);
            float r2v = wred64(sq[c]);
            if (lane == 0) { atomicAdd(&st[c], r1v); atomicAdd(&st[4 + c], r2v); }
        }
    }

    // phase 4b: grouped 3x3 conv into x2_lds (thread-owned positions; low reg pressure)
#pragma unroll
    for (int pp = 0; pp < 4; ++pp) {
        const int p = tid + pp * 1024;
#pragma unroll
        for (int o = 0; o < 4; ++o) x2_lds[o][p] = b3_s[o];
    }
#pragma unroll
    for (int i = 0; i < 4; ++i) {
#pragma unroll
        for (int pp = 0; pp < 4; ++pp) {
            const int p = tid + pp * 1024, h = p >> 6, w = p & 63;
            float v[9];
#pragma unroll
            for (int dy = 0; dy < 3; ++dy)
#pragma unroll
                for (int dx = 0; dx < 3; ++dx) v[dy * 3 + dx] = gpad[i][h + dy][w + dx];
#pragma unroll
            for (int o = 0; o < 4; ++o) {
                float a = 0.f;
#pragma unroll
                for (int j = 0; j < 9; ++j) a += v[j] * wk[o][i][j];
                x2_lds[o][p] += a;
            }
        }
    }
    // x2 means for a2
    {
#pragma unroll
        for (int o = 0; o < 4; ++o) {
            float sx = 0.f;
#pragma unroll
            for (int pp = 0; pp < 4; ++pp) sx += x2_lds[o][tid + pp * 1024];
            float r3v = wred64(sx);
            if (lane == 0) atomicAdd(&st[8 + o], r3v);
        }
    }
    __syncthreads();

    // phase 5: stats finalize; a1 = softmax(gn_b) exactly; a2 = softmax(mean x2)
    if (tid == 0) {
        float m1 = -1e30f, m2 = -1e30f;
#pragma unroll
        for (int c = 0; c < 4; ++c) {
            float mu = st[c] * (1.f / 4096.f);
            float var = st[4 + c] * (1.f / 4096.f) - mu * mu;
            mu_s[c] = mu;
            rs_s[c] = rsqrtf(var + EPS);
            if (gnb_s[c] > m1) m1 = gnb_s[c];
            float mx = st[8 + c] * (1.f / 4096.f);
            if (mx > m2) m2 = mx;
        }
        float sum1 = 0.f, sum2 = 0.f, e1[4], e2[4];
#pragma unroll
        for (int c = 0; c < 4; ++c) {
            e1[c] = expf(gnb_s[c] - m1); sum1 += e1[c];
            e2[c] = expf(st[8 + c] * (1.f / 4096.f) - m2); sum2 += e2[c];
        }
#pragma unroll
        for (int c = 0; c < 4; ++c) { a1_s[c] = e1[c] / sum1; a2_s[c] = e2[c] / sum2; }
    }
    __syncthreads();

    // phase 6: wmap + sigmoid + residual
    {
        const size_t gbase = ((size_t)(b * 256 + c0)) * 4096;
#pragma unroll
        for (int pp = 0; pp < 4; ++pp) {
            const int p = tid + pp * 1024, h = p >> 6, w = p & 63;
            float wm = 0.f;
#pragma unroll
            for (int c = 0; c < 4; ++c) {
                float gv = gpad[c][h + 1][w + 1];
                float gate = gv * sigh[c][h] * sigw[c][w];
                float x1v = (gate - mu_s[c]) * rs_s[c] * gnw_s[c] + gnb_s[c];
                wm += a1_s[c] * x2_lds[c][p] + a2_s[c] * x1v;
            }
            float sg = 1.f / (1.f + expf(-wm));
#pragma unroll
            for (int c = 0; c < 4; ++c) {
                size_t idx = gbase + (size_t)c * 4096 + p;
                out[idx] = x[idx] + gpad[c][h + 1][w + 1] * sg;
            }
        }
    }
}

// ===================== LN2 with transposed bf16 output y2T[b][p][256] =====================
__global__ __launch_bounds__(256) void ln2T_kernel(const float* __restrict__ in,
    const float* __restrict__ w, const float* __restrict__ bias, u16* __restrict__ outT)
{
    __shared__ float tile[256][33];
    __shared__ float reds[8][32], redq[8][32];
    __shared__ float mus[32], rss[32];
    __shared__ float ws_[256], bs_[256];

    const int b = blockIdx.y, p0 = blockIdx.x * 32;
    const int t = threadIdx.x, q = t >> 5, p = t & 31;
    ws_[t] = w[t]; bs_[t] = bias[t];

    const float* src = in + (size_t)b * 256 * 4096 + p0 + p;
    float s = 0.f, s2 = 0.f;
#pragma unroll 8
    for (int j = 0; j < 32; ++j) {
        int c = j * 8 + q;
        float v = src[(size_t)c * 4096];
        tile[c][p] = v; s += v; s2 += v * v;
    }
    reds[q][p] = s; redq[q][p] = s2;
    __syncthreads();
    if (t < 32) {
        float ss = 0.f, qq = 0.f;
#pragma unroll
        for (int k = 0; k < 8; ++k) { ss += reds[k][t]; qq += redq[k][t]; }
        float mu = ss * (1.f / 256.f);
        float var = qq * (1.f / 256.f) - mu * mu;
        mus[t] = mu; rss[t] = rsqrtf(var + EPS);
    }
    __syncthreads();
    const int pr = t >> 3, ch = t & 7;
    const float muv = mus[pr], rsv = rss[pr];
    unsigned pk[16];
#pragma unroll
    for (int jj = 0; jj < 16; ++jj) {
        int c = ch * 32 + jj * 2;
        float v0 = (tile[c][pr] - muv) * rsv * ws_[c] + bs_[c];
        float v1 = (tile[c + 1][pr] - muv) * rsv * ws_[c + 1] + bs_[c + 1];
        pk[jj] = (unsigned)f2bf(v0) | ((unsigned)f2bf(v1) << 16);
    }
    u16* dst = outT + ((size_t)b * 4096 + p0 + pr) * 256 + ch * 32;
#pragma unroll
    for (int k = 0; k < 4; ++k) {
        uint4 ov; ov.x = pk[k*4]; ov.y = pk[k*4+1]; ov.z = pk[k*4+2]; ov.w = pk[k*4+3];
        ((uint4*)dst)[k] = ov;
    }
}

// ===================== MFMA GEMM1: z[b][1360][4096] (c-major) = w_in . y2T^T =====================
// grid (32, 11, nb), block 256 (4 waves 2x2), 128x128 tile, BK=64.
__global__ __launch_bounds__(256, 3) void gemm1_kernel(
    const u16* __restrict__ Abf, const u16* __restrict__ Bt, u16* __restrict__ Z)
{
    union SMEM { struct { u16 A[128][72]; u16 B[128][72]; } ab; u16 T[128][136]; };
    __shared__ SMEM sm;
    const int bz = blockIdx.z;
    const int n0 = blockIdx.x * 128, m0 = blockIdx.y * 128;
    const int tid = threadIdx.x;
    const int l = tid & 63, wv = tid >> 6, wr = wv >> 1, wc = wv & 1;
    const int lr = l & 15, lg = l >> 4;
    const int srow = tid >> 1, shalf = tid & 1;

    f32x4 acc[4][4];
    const f32x4 fzero = {0.f, 0.f, 0.f, 0.f};
#pragma unroll
    for (int i = 0; i < 4; ++i)
#pragma unroll
        for (int j = 0; j < 4; ++j) acc[i][j] = fzero;

    const u16* gA = Abf + (size_t)(m0 + srow) * 256 + shalf * 32;
    const u16* gB = Bt + ((size_t)bz * 4096 + n0 + srow) * 256 + shalf * 32;
    const bool aok = (m0 + srow) < 1360;
    const uint4 z4 = {0u, 0u, 0u, 0u};

#pragma unroll 1
    for (int kt = 0; kt < 4; ++kt) {
        uint4 av[4], bv[4];
#pragma unroll
        for (int i = 0; i < 4; ++i) {
            av[i] = aok ? ((const uint4*)(gA + kt * 64))[i] : z4;
            bv[i] = ((const uint4*)(gB + kt * 64))[i];
        }
        __syncthreads();
#pragma unroll
        for (int i = 0; i < 4; ++i) {
            ((uint4*)&sm.ab.A[srow][shalf * 32])[i] = av[i];
            ((uint4*)&sm.ab.B[srow][shalf * 32])[i] = bv[i];
        }
        __syncthreads();
#pragma unroll
        for (int kc = 0; kc < 2; ++kc) {
            bf16x8 af[4], bfr[4];
#pragma unroll
            for (int mf = 0; mf < 4; ++mf)
                af[mf] = *(const bf16x8*)&sm.ab.A[wr * 64 + mf * 16 + lr][kc * 32 + lg * 8];
#pragma unroll
            for (int nf = 0; nf < 4; ++nf)
                bfr[nf] = *(const bf16x8*)&sm.ab.B[wc * 64 + nf * 16 + lr][kc * 32 + lg * 8];
#pragma unroll
            for (int mf = 0; mf < 4; ++mf)
#pragma unroll
                for (int nf = 0; nf < 4; ++nf)
                    acc[mf][nf] = __builtin_amdgcn_mfma_f32_16x16x32_bf16(af[mf], bfr[nf], acc[mf][nf], 0, 0, 0);
        }
    }
    // epilogue: stage [m][n] bf16 tile, linear coalesced store (c-major)
    __syncthreads();
#pragma unroll
    for (int mf = 0; mf < 4; ++mf)
#pragma unroll
        for (int nf = 0; nf < 4; ++nf) {
            int ml = wr * 64 + mf * 16 + lg * 4;
            int nl = wc * 64 + nf * 16 + lr;
            f32x4 c = acc[mf][nf];
            sm.T[ml + 0][nl] = f2bf(c.x);
            sm.T[ml + 1][nl] = f2bf(c.y);
            sm.T[ml + 2][nl] = f2bf(c.z);
            sm.T[ml + 3][nl] = f2bf(c.w);
        }
    __syncthreads();
    {
        const int gm = m0 + srow;
        if (gm < 1360) {
            u16* drow = Z + (size_t)bz * 1360 * 4096 + (size_t)gm * 4096 + n0 + shalf * 64;
#pragma unroll
            for (int k = 0; k < 8; ++k)
                ((uint4*)drow)[k] = ((const uint4*)&sm.T[srow][shalf * 64])[k];
        }
    }
}

// ===================== spatial-major depthwise 3x3 + exact GELU: t[b][680][4096] =====================
// grid (680, 4, nb), block 256. LDS-staged 18x66 tile per plane, 4-wide strips per thread.
__global__ __launch_bounds__(256) void dwgelu_kernel(
    const u16* __restrict__ z, const float* __restrict__ wdw, u16* __restrict__ t)
{
    __shared__ u16 zt[2][18][66];
    const int bz = blockIdx.z;
    const int c  = blockIdx.x;        // 0..679
    const int r0 = blockIdx.y * 16;
    const int tid = threadIdx.x;
    const u16* Z = z + (size_t)bz * 1360 * 4096;

#pragma unroll
    for (int sel = 0; sel < 2; ++sel) {
        const u16* src = Z + (size_t)(c + sel * 680) * 4096;
        for (int i = tid; i < 18 * 66; i += 256) {
            int rr = i / 66, cc = i % 66;
            int h = r0 - 1 + rr, w = cc - 1;
            u16 v = 0;
            if (h >= 0 && h < 64 && w >= 0 && w < 64) v = src[h * 64 + w];
            zt[sel][rr][cc] = v;
        }
    }
    __syncthreads();

    float w1r[9], w2r[9];
#pragma unroll
    for (int j = 0; j < 9; ++j) {
        w1r[j] = wdw[c * 9 + j];
        w2r[j] = wdw[(c + 680) * 9 + j];
    }
    const int hl = tid >> 4;          // 0..15
    const int w0 = (tid & 15) * 4;    // 0..60

    float d1a[4] = {0.f, 0.f, 0.f, 0.f}, d2a[4] = {0.f, 0.f, 0.f, 0.f};
#pragma unroll
    for (int dy = 0; dy < 3; ++dy) {
        float r1[6], r2[6];
#pragma unroll
        for (int k = 0; k < 6; ++k) {
            r1[k] = bf2f(zt[0][hl + dy][w0 + k]);
            r2[k] = bf2f(zt[1][hl + dy][w0 + k]);
        }
#pragma unroll
        for (int p = 0; p < 4; ++p) {
            d1a[p] += r1[p] * w1r[dy * 3] + r1[p + 1] * w1r[dy * 3 + 1] + r1[p + 2] * w1r[dy * 3 + 2];
            d2a[p] += r2[p] * w2r[dy * 3] + r2[p + 1] * w2r[dy * 3 + 1] + r2[p + 2] * w2r[dy * 3 + 2];
        }
    }
    unsigned pk[2];
#pragma unroll
    for (int k = 0; k < 2; ++k) {
        float da = d1a[k * 2], db = d1a[k * 2 + 1];
        float g0 = 0.5f * da * (1.f + erff(da * 0.70710678118654752f)) * d2a[k * 2];
        float g1 = 0.5f * db * (1.f + erff(db * 0.70710678118654752f)) * d2a[k * 2 + 1];
        pk[k] = (unsigned)f2bf(g0) | ((unsigned)f2bf(g1) << 16);
    }
    u16* dst = t + (size_t)bz * 680 * 4096 + (size_t)c * 4096 + (r0 + hl) * 64 + w0;
    *(uint2*)dst = make_uint2(pk[0], pk[1]);
}

// ===================== LDS-tiled transpose: t[b][680][4096] -> tT[b][4096][680] =====================
// grid (64, 11, nb), block 256.
__global__ __launch_bounds__(256) void transpose_kernel(
    const u16* __restrict__ t, u16* __restrict__ tT)
{
    __shared__ u16 tile[64][68];
    const int bz = blockIdx.z;
    const int p0 = blockIdx.x * 64;
    const int c0 = blockIdx.y * 64;
    const int tid = threadIdx.x;
    const u16* src = t + (size_t)bz * 680 * 4096;
    u16* dst = tT + (size_t)bz * 4096 * 680;

#pragma unroll
    for (int it = 0; it < 4; ++it) {
        int i = tid + it * 256;
        int r = i >> 4, cc = (i & 15) * 4;
        uint2 v = make_uint2(0u, 0u);
        if (c0 + r < 680) v = *(const uint2*)&src[(size_t)(c0 + r) * 4096 + p0 + cc];
        *(uint2*)&tile[r][cc] = v;
    }
    __syncthreads();
#pragma unroll
    for (int it = 0; it < 4; ++it) {
        int i = tid + it * 256;
        int pp = i >> 4, cc = (i & 15) * 4;
        if (c0 + cc < 680) {
            u16 a = tile[cc][pp], b = tile[cc + 1][pp];
            u16 c = tile[cc + 2][pp], d = tile[cc + 3][pp];
            uint2 v;
            v.x = (unsigned)a | ((unsigned)b << 16);
            v.y = (unsigned)c | ((unsigned)d << 16);
            *(uint2*)&dst[(size_t)(p0 + pp) * 680 + c0 + cc] = v;
        }
    }
}

// ===================== MFMA GEMM2: out[b][256][4096] += w_out . t =====================
// grid (32, 2, nb), block 256, 128x128 tile, BK=64, K=680 with tail guards.
__global__ __launch_bounds__(256, 3) void gemm2_kernel(
    const u16* __restrict__ Abf, const u16* __restrict__ Bt, float* __restrict__ out)
{
    __shared__ u16 As[128][72];
    __shared__ u16 Bs[128][72];
    const int bz = blockIdx.z;
    const int n0 = blockIdx.x * 128, m0 = blockIdx.y * 128;
    const int tid = threadIdx.x;
    const int l = tid & 63, wv = tid >> 6, wr = wv >> 1, wc = wv & 1;
    const int lr = l & 15, lg = l >> 4;
    const int srow = tid >> 1, shalf = tid & 1;

    f32x4 acc[4][4];
    const f32x4 fzero = {0.f, 0.f, 0.f, 0.f};
#pragma unroll
    for (int i = 0; i < 4; ++i)
#pragma unroll
        for (int j = 0; j < 4; ++j) acc[i][j] = fzero;

    const u16* gA = Abf + (size_t)(m0 + srow) * 680;
    const u16* gB = Bt + ((size_t)bz * 4096 + n0 + srow) * 680;
    const uint4 z4 = {0u, 0u, 0u, 0u};

#pragma unroll 1
    for (int kt = 0; kt < 11; ++kt) {
        const int k0 = kt * 64 + shalf * 32;
        uint4 av[4], bv[4];
#pragma unroll
        for (int i = 0; i < 4; ++i) {
            int kk = k0 + i * 8;
            bool ok = (kk + 8) <= 680;
            av[i] = ok ? *(const uint4*)(gA + kk) : z4;
            bv[i] = ok ? *(const uint4*)(gB + kk) : z4;
        }
        __syncthreads();
#pragma unroll
        for (int i = 0; i < 4; ++i) {
            ((uint4*)&As[srow][shalf * 32])[i] = av[i];
            ((uint4*)&Bs[srow][shalf * 32])[i] = bv[i];
        }
        __syncthreads();
#pragma unroll
        for (int kc = 0; kc < 2; ++kc) {
            bf16x8 af[4], bfr[4];
#pragma unroll
            for (int mf = 0; mf < 4; ++mf)
                af[mf] = *(const bf16x8*)&As[wr * 64 + mf * 16 + lr][kc * 32 + lg * 8];
#pragma unroll
            for (int nf = 0; nf < 4; ++nf)
                bfr[nf] = *(const bf16x8*)&Bs[wc * 64 + nf * 16 + lr][kc * 32 + lg * 8];
#pragma unroll
            for (int mf = 0; mf < 4; ++mf)
#pragma unroll
                for (int nf = 0; nf < 4; ++nf)
                    acc[mf][nf] = __builtin_amdgcn_mfma_f32_16x16x32_bf16(af[mf], bfr[nf], acc[mf][nf], 0, 0, 0);
        }
    }
#pragma unroll
    for (int mf = 0; mf < 4; ++mf)
#pragma unroll
        for (int nf = 0; nf < 4; ++nf) {
            int m = m0 + wr * 64 + mf * 16 + lg * 4;
            int n = n0 + wc * 64 + nf * 16 + lr;
            size_t base = ((size_t)bz * 256 + m) * 4096 + n;
            f32x4 c = acc[mf][nf];
#pragma unroll
            for (int r = 0; r < 4; ++r) {
                size_t idx = base + (size_t)r * 4096;
                out[idx] = out[idx] + c[r];
            }
        }
}

// ===================== host =====================
extern "C" void kernel_launch(void* const* d_in, const int* in_sizes, int n_in,
                              void* d_out, int out_size, void* d_ws, size_t ws_size,
                              hipStream_t stream)
{
    const float* x     = (const float*)d_in[0];
    const float* ln1w  = (const float*)d_in[1];
    const float* ln1b  = (const float*)d_in[2];
    const float* w1    = (const float*)d_in[3];
    const float* b1    = (const float*)d_in[4];
    const float* w3    = (const float*)d_in[5];
    const float* b3    = (const float*)d_in[6];
    const float* gnw   = (const float*)d_in[7];
    const float* gnb   = (const float*)d_in[8];
    const float* ln2w  = (const float*)d_in[9];
    const float* ln2b  = (const float*)d_in[10];
    const float* w_in  = (const float*)d_in[11];
    const float* w_dw  = (const float*)d_in[12];
    const float* w_out = (const float*)d_in[13];
    float* out = (float*)d_out;

    char* ws = (char*)d_ws;
    // layout
    const size_t OFF_RS  = 131072;
    const size_t OFF_Y2T = 262144;
    const size_t OFF_WIB = 17039360;       // y2T end: 262144 + 16777216
    const size_t OFF_WOB = 17735680;       // wib end
    const size_t OFF_Z   = 18087936;       // wob end 18083840, pad
    const size_t Z_FULL  = 89128960;       // 8*1360*4096*2
    const size_t OFF_T   = OFF_Z + Z_FULL; // 107216896
    const size_t T_FULL  = 44564480;       // 8*680*4096*2
    const size_t NEED_FULL = OFF_T + T_FULL; // 151781376

    float* mu_g = (float*)(ws);
    float* rs_g = (float*)(ws + OFF_RS);
    u16*   y2T  = (u16*)(ws + OFF_Y2T);
    u16*   wib  = (u16*)(ws + OFF_WIB);
    u16*   wob  = (u16*)(ws + OFF_WOB);
    const bool full = ws_size >= NEED_FULL;

    prep_kernel<<<dim3(1360), dim3(256), 0, stream>>>(w_in, w_out, wib, wob);
    ln_stats_kernel<<<dim3(64, 8), dim3(256), 0, stream>>>(x, mu_g, rs_g);
    attn_kernel<<<dim3(64, 8), dim3(1024), 0, stream>>>(x, mu_g, rs_g, ln1w, ln1b,
                                                        w1, b1, w3, b3, gnw, gnb, out);
    ln2T_kernel<<<dim3(128, 8), dim3(256), 0, stream>>>(out, ln2w, ln2b, y2T);

    if (full) {
        u16* z   = (u16*)(ws + OFF_Z);
        u16* t   = (u16*)(ws + OFF_T);
        u16* tT  = (u16*)(ws + OFF_Z);     // overlays z (dead after dwgelu)
        gemm1_kernel<<<dim3(32, 11, 8), dim3(256), 0, stream>>>(wib, y2T, z);
        dwgelu_kernel<<<dim3(680, 4, 8), dim3(256), 0, stream>>>(z, w_dw, t);
        transpose_kernel<<<dim3(64, 11, 8), dim3(256), 0, stream>>>(t, tT);
        gemm2_kernel<<<dim3(32, 2, 8), dim3(256), 0, stream>>>(wob, tT, out);
    } else {
        const size_t Z1 = (size_t)1360 * 4096 * 2;   // 11141120
        const size_t T1 = (size_t)680 * 4096 * 2;    // 5570560
        u16* z  = (u16*)(ws + OFF_Z);
        u16* t  = (u16*)(ws + OFF_Z + Z1);
        u16* tT = (u16*)(ws + OFF_Z + Z1 + T1);
        for (int b = 0; b < 8; ++b) {
            gemm1_kernel<<<dim3(32, 11, 1), dim3(256), 0, stream>>>(
                wib, y2T + (size_t)b * 4096 * 256, z);
            dwgelu_kernel<<<dim3(680, 4, 1), dim3(256), 0, stream>>>(z, w_dw, t);
            transpose_kernel<<<dim3(64, 11, 1), dim3(256), 0, stream>>>(t, tT);
            gemm2_kernel<<<dim3(32, 2, 1), dim3(256), 0, stream>>>(
                wob, tT, out + (size_t)b * 256 * 4096);
        }
    }
}

// Round 6
// 341.814 us; speedup vs baseline: 6.2870x; 1.5124x over previous
//
#include <hip/hip_runtime.h>
#include <math.h>

#define EPS 1e-5f

typedef unsigned short u16;
typedef __attribute__((ext_vector_type(8))) short bf16x8;
typedef __attribute__((ext_vector_type(4))) float f32x4;

__device__ __forceinline__ u16 f2bf(float f) {
    unsigned u = __builtin_bit_cast(unsigned, f);
    u += 0x7FFFu + ((u >> 16) & 1u);
    return (u16)(u >> 16);
}
__device__ __forceinline__ float bf2f(u16 h) {
    return __builtin_bit_cast(float, (unsigned)h << 16);
}
__device__ __forceinline__ float wred64(float v) {
#pragma unroll
    for (int off = 32; off > 0; off >>= 1) v += __shfl_down(v, off, 64);
    return v;
}
// async global->LDS, 16B per lane, dest = wave-uniform base + lane*16
__device__ __forceinline__ void gload16(const u16* g, u16* l) {
    __builtin_amdgcn_global_load_lds(
        (const __attribute__((address_space(1))) void*)g,
        (__attribute__((address_space(3))) void*)l, 16, 0, 0);
}

// ===================== weight prep: fp32 -> bf16 (wob zero-padded K 680->704) =====================
__global__ __launch_bounds__(256) void prep_kernel(
    const float* __restrict__ w_in, const float* __restrict__ w_out,
    u16* __restrict__ wib, u16* __restrict__ wob)
{
    int i = blockIdx.x * 256 + threadIdx.x;
    if (i < 1360 * 256) wib[i] = f2bf(w_in[i]);
    if (i < 256 * 704) {
        int m = i / 704, k = i - m * 704;
        wob[i] = (k < 680) ? f2bf(w_out[m * 680 + k]) : (u16)0;
    }
}

// ===================== LN1 stats only (mu, rsqrt per position) =====================
__global__ __launch_bounds__(256) void ln_stats_kernel(const float* __restrict__ x,
    float* __restrict__ mu_g, float* __restrict__ rs_g)
{
    __shared__ float r1[4][64], r2[4][64];
    const int b = blockIdx.y, p0 = blockIdx.x * 64;
    const int t = threadIdx.x, p = t & 63, q = t >> 6;
    const float* src = x + (size_t)b * 256 * 4096 + (size_t)q * 64 * 4096 + p0 + p;
    float s = 0.f, s2 = 0.f;
#pragma unroll 8
    for (int j = 0; j < 64; ++j) { float v = src[(size_t)j * 4096]; s += v; s2 += v * v; }
    r1[q][p] = s; r2[q][p] = s2;
    __syncthreads();
    if (t < 64) {
        float ss = r1[0][t] + r1[1][t] + r1[2][t] + r1[3][t];
        float qq = r2[0][t] + r2[1][t] + r2[2][t] + r2[3][t];
        float mu = ss * (1.f / 256.f);
        float var = qq * (1.f / 256.f) - mu * mu;
        mu_g[(size_t)b * 4096 + p0 + t] = mu;
        rs_g[(size_t)b * 4096 + p0 + t] = rsqrtf(var + EPS);
    }
}

// ===================== fused LN1-apply + attn_ema + residual =====================
__global__ __launch_bounds__(1024, 4) void attn_kernel(
    const float* __restrict__ x, const float* __restrict__ mu_g, const float* __restrict__ rs_g,
    const float* __restrict__ ln1w, const float* __restrict__ ln1b,
    const float* __restrict__ w1, const float* __restrict__ b1,
    const float* __restrict__ w3, const float* __restrict__ b3,
    const float* __restrict__ gn_w, const float* __restrict__ gn_b,
    float* __restrict__ out)
{
    __shared__ float gpad[4][66][66];
    __shared__ float x2_lds[4][4096];
    __shared__ float xh_s[4][64], xw_s[4][64], sigh[4][64], sigw[4][64];
    __shared__ float wk[4][4][9];
    __shared__ float st[12];
    __shared__ float b3_s[4], gnw_s[4], gnb_s[4], lw_s[4], lb_s[4];
    __shared__ float mu_s[4], rs_s[4], a1_s[4], a2_s[4];

    const int b  = blockIdx.y;
    const int Gi = blockIdx.x >> 3;
    const int Hi = blockIdx.x & 7;
    const int c0 = Hi * 32 + Gi * 4;
    const int tid = threadIdx.x;
    const int lane = tid & 63, wav = tid >> 6;

    float* gl = &gpad[0][0][0];
    for (int i = tid; i < 4 * 66 * 66; i += 1024) gl[i] = 0.f;
    if (tid < 256) xw_s[tid >> 6][tid & 63] = 0.f;
    if (tid < 12) st[tid] = 0.f;
    if (tid < 144) (&wk[0][0][0])[tid] = w3[Hi * 144 + tid];
    if (tid < 4) {
        b3_s[tid]  = b3[Hi * 4 + tid];
        gnw_s[tid] = gn_w[Hi * 4 + tid];
        gnb_s[tid] = gn_b[Hi * 4 + tid];
        lw_s[tid]  = ln1w[c0 + tid];
        lb_s[tid]  = ln1b[c0 + tid];
    }
    __syncthreads();

    {
        const float* src = x + ((size_t)(b * 256 + c0)) * 4096;
        const float* mug = mu_g + (size_t)b * 4096;
        const float* rsg = rs_g + (size_t)b * 4096;
#pragma unroll
        for (int it = 0; it < 16; ++it) {
            const int c = it >> 2;
            const int p = tid + (it & 3) * 1024;
            const int h = p >> 6, ww = p & 63;
            float v = src[(size_t)c * 4096 + p];
            gpad[c][h + 1][ww + 1] = (v - mug[p]) * rsg[p] * lw_s[c] + lb_s[c];
        }
    }
    __syncthreads();

    {
        float colp[4] = {0.f, 0.f, 0.f, 0.f};
#pragma unroll
        for (int c = 0; c < 4; ++c) {
#pragma unroll
            for (int rr = 0; rr < 4; ++rr) {
                int h = wav + rr * 16;
                float v = gpad[c][h + 1][lane + 1];
                colp[c] += v;
                float rsum = wred64(v);
                if (lane == 0) xh_s[c][h] = rsum;
            }
        }
#pragma unroll
        for (int c = 0; c < 4; ++c) atomicAdd(&xw_s[c][lane], colp[c]);
    }
    __syncthreads();

    if (tid < 512) {
        int o = tid >> 7, s = tid & 127;
        float acc = b1[Hi * 4 + o];
#pragma unroll
        for (int i = 0; i < 4; ++i) {
            float cm = (s < 64 ? xh_s[i][s] : xw_s[i][s - 64]) * (1.f / 64.f);
            acc += w1[(Hi * 4 + o) * 4 + i] * cm;
        }
        float sg = 1.f / (1.f + expf(-acc));
        if (s < 64) sigh[o][s] = sg; else sigw[o][s - 64] = sg;
    }
    __syncthreads();

    {
        float s1[4] = {0.f,0.f,0.f,0.f}, sq[4] = {0.f,0.f,0.f,0.f};
#pragma unroll
        for (int pp = 0; pp < 4; ++pp) {
            const int p = tid + pp * 1024, h = p >> 6, w = p & 63;
#pragma unroll
            for (int c = 0; c < 4; ++c) {
                float gate = gpad[c][h + 1][w + 1] * sigh[c][h] * sigw[c][w];
                s1[c] += gate; sq[c] += gate * gate;
            }
        }
#pragma unroll
        for (int c = 0; c < 4; ++c) {
            float r1v = wred64(s1[c]);
            float r2v = wred64(sq[c]);
            if (lane == 0) { atomicAdd(&st[c], r1v); atomicAdd(&st[4 + c], r2v); }
        }
    }

#pragma unroll
    for (int pp = 0; pp < 4; ++pp) {
        const int p = tid + pp * 1024;
#pragma unroll
        for (int o = 0; o < 4; ++o) x2_lds[o][p] = b3_s[o];
    }
#pragma unroll
    for (int i = 0; i < 4; ++i) {
#pragma unroll
        for (int pp = 0; pp < 4; ++pp) {
            const int p = tid + pp * 1024, h = p >> 6, w = p & 63;
            float v[9];
#pragma unroll
            for (int dy = 0; dy < 3; ++dy)
#pragma unroll
                for (int dx = 0; dx < 3; ++dx) v[dy * 3 + dx] = gpad[i][h + dy][w + dx];
#pragma unroll
            for (int o = 0; o < 4; ++o) {
                float a = 0.f;
#pragma unroll
                for (int j = 0; j < 9; ++j) a += v[j] * wk[o][i][j];
                x2_lds[o][p] += a;
            }
        }
    }
    {
#pragma unroll
        for (int o = 0; o < 4; ++o) {
            float sx = 0.f;
#pragma unroll
            for (int pp = 0; pp < 4; ++pp) sx += x2_lds[o][tid + pp * 1024];
            float r3v = wred64(sx);
            if (lane == 0) atomicAdd(&st[8 + o], r3v);
        }
    }
    __syncthreads();

    if (tid == 0) {
        float m1 = -1e30f, m2 = -1e30f;
#pragma unroll
        for (int c = 0; c < 4; ++c) {
            float mu = st[c] * (1.f / 4096.f);
            float var = st[4 + c] * (1.f / 4096.f) - mu * mu;
            mu_s[c] = mu;
            rs_s[c] = rsqrtf(var + EPS);
            if (gnb_s[c] > m1) m1 = gnb_s[c];
            float mx = st[8 + c] * (1.f / 4096.f);
            if (mx > m2) m2 = mx;
        }
        float sum1 = 0.f, sum2 = 0.f, e1[4], e2[4];
#pragma unroll
        for (int c = 0; c < 4; ++c) {
            e1[c] = expf(gnb_s[c] - m1); sum1 += e1[c];
            e2[c] = expf(st[8 + c] * (1.f / 4096.f) - m2); sum2 += e2[c];
        }
#pragma unroll
        for (int c = 0; c < 4; ++c) { a1_s[c] = e1[c] / sum1; a2_s[c] = e2[c] / sum2; }
    }
    __syncthreads();

    {
        const size_t gbase = ((size_t)(b * 256 + c0)) * 4096;
#pragma unroll
        for (int pp = 0; pp < 4; ++pp) {
            const int p = tid + pp * 1024, h = p >> 6, w = p & 63;
            float wm = 0.f;
#pragma unroll
            for (int c = 0; c < 4; ++c) {
                float gv = gpad[c][h + 1][w + 1];
                float gate = gv * sigh[c][h] * sigw[c][w];
                float x1v = (gate - mu_s[c]) * rs_s[c] * gnw_s[c] + gnb_s[c];
                wm += a1_s[c] * x2_lds[c][p] + a2_s[c] * x1v;
            }
            float sg = 1.f / (1.f + expf(-wm));
#pragma unroll
            for (int c = 0; c < 4; ++c) {
                size_t idx = gbase + (size_t)c * 4096 + p;
                out[idx] = x[idx] + gpad[c][h + 1][w + 1] * sg;
            }
        }
    }
}

// ===================== LN2 with transposed bf16 output y2T[b][p][256] =====================
__global__ __launch_bounds__(256) void ln2T_kernel(const float* __restrict__ in,
    const float* __restrict__ w, const float* __restrict__ bias, u16* __restrict__ outT)
{
    __shared__ float tile[256][33];
    __shared__ float reds[8][32], redq[8][32];
    __shared__ float mus[32], rss[32];
    __shared__ float ws_[256], bs_[256];

    const int b = blockIdx.y, p0 = blockIdx.x * 32;
    const int t = threadIdx.x, q = t >> 5, p = t & 31;
    ws_[t] = w[t]; bs_[t] = bias[t];

    const float* src = in + (size_t)b * 256 * 4096 + p0 + p;
    float s = 0.f, s2 = 0.f;
#pragma unroll 8
    for (int j = 0; j < 32; ++j) {
        int c = j * 8 + q;
        float v = src[(size_t)c * 4096];
        tile[c][p] = v; s += v; s2 += v * v;
    }
    reds[q][p] = s; redq[q][p] = s2;
    __syncthreads();
    if (t < 32) {
        float ss = 0.f, qq = 0.f;
#pragma unroll
        for (int k = 0; k < 8; ++k) { ss += reds[k][t]; qq += redq[k][t]; }
        float mu = ss * (1.f / 256.f);
        float var = qq * (1.f / 256.f) - mu * mu;
        mus[t] = mu; rss[t] = rsqrtf(var + EPS);
    }
    __syncthreads();
    const int pr = t >> 3, ch = t & 7;
    const float muv = mus[pr], rsv = rss[pr];
    unsigned pk[16];
#pragma unroll
    for (int jj = 0; jj < 16; ++jj) {
        int c = ch * 32 + jj * 2;
        float v0 = (tile[c][pr] - muv) * rsv * ws_[c] + bs_[c];
        float v1 = (tile[c + 1][pr] - muv) * rsv * ws_[c + 1] + bs_[c + 1];
        pk[jj] = (unsigned)f2bf(v0) | ((unsigned)f2bf(v1) << 16);
    }
    u16* dst = outT + ((size_t)b * 4096 + p0 + pr) * 256 + ch * 32;
#pragma unroll
    for (int k = 0; k < 4; ++k) {
        uint4 ov; ov.x = pk[k*4]; ov.y = pk[k*4+1]; ov.z = pk[k*4+2]; ov.w = pk[k*4+3];
        ((uint4*)dst)[k] = ov;
    }
}

// ===================== MFMA GEMM1: z[b][1360][4096] = w_in . y2T^T =====================
// grid 352*nb (1D, XCD-chunked m-fastest work order), block 256, 128x128 tile, BK=64.
// global_load_lds staging, XOR chunk-swizzle on source + ds_read (both sides).
__global__ __launch_bounds__(256, 2) void gemm1_kernel(
    const u16* __restrict__ Abf, const u16* __restrict__ Bt, u16* __restrict__ Z)
{
    union SMEM { struct { u16 A[128][64]; u16 B[128][64]; } ab; u16 T[128][136]; };
    __shared__ SMEM sm;

    const int bid = blockIdx.x;
    const int cpx = gridDim.x >> 3;
    const int W = (bid & 7) * cpx + (bid >> 3);     // bijective (gridDim.x % 8 == 0)
    const int bz = W / 352;
    const int rem = W - bz * 352;
    const int nb = rem / 11;
    const int mb = rem - nb * 11;
    const int m0 = mb * 128, n0 = nb * 128;

    const int tid = threadIdx.x;
    const int w = tid >> 6, l = tid & 63;
    const int wr = w >> 1, wc = w & 1;
    const int lr = l & 15, lg = l >> 4;
    const int lr8 = l >> 3, lc8 = l & 7;
    const int csw = (lc8 ^ lr8) * 8;    // pre-swizzled source chunk offset (elems)

    f32x4 acc[4][4];
    const f32x4 fzero = {0.f, 0.f, 0.f, 0.f};
#pragma unroll
    for (int i = 0; i < 4; ++i)
#pragma unroll
        for (int j = 0; j < 4; ++j) acc[i][j] = fzero;

#pragma unroll 1
    for (int kt = 0; kt < 4; ++kt) {
        __syncthreads();
        const int kOff = kt * 64;
#pragma unroll
        for (int i = 0; i < 4; ++i) {
            const int j = w * 4 + i;
            int ar = m0 + j * 8 + lr8;
            if (ar >= 1360) ar = 0;    // clamp; garbage rows never stored
            gload16(Abf + (size_t)ar * 256 + kOff + csw, &sm.ab.A[j * 8][0]);
            gload16(Bt + ((size_t)bz * 4096 + n0 + j * 8 + lr8) * 256 + kOff + csw,
                    &sm.ab.B[j * 8][0]);
        }
        __syncthreads();   // drains vmcnt: staged tile ready
#pragma unroll
        for (int kc = 0; kc < 2; ++kc) {
            bf16x8 af[4], bfr[4];
#pragma unroll
            for (int mf = 0; mf < 4; ++mf) {
                const int R = wr * 64 + mf * 16 + lr;
                af[mf] = *(const bf16x8*)&sm.ab.A[R][(((kc << 2) | lg) ^ (R & 7)) << 3];
            }
#pragma unroll
            for (int nf = 0; nf < 4; ++nf) {
                const int R = wc * 64 + nf * 16 + lr;
                bfr[nf] = *(const bf16x8*)&sm.ab.B[R][(((kc << 2) | lg) ^ (R & 7)) << 3];
            }
#pragma unroll
            for (int mf = 0; mf < 4; ++mf)
#pragma unroll
                for (int nf = 0; nf < 4; ++nf)
                    acc[mf][nf] = __builtin_amdgcn_mfma_f32_16x16x32_bf16(af[mf], bfr[nf], acc[mf][nf], 0, 0, 0);
        }
    }
    // epilogue: stage bf16 [m][n] tile in LDS, linear coalesced c-major store
    __syncthreads();
#pragma unroll
    for (int mf = 0; mf < 4; ++mf)
#pragma unroll
        for (int nf = 0; nf < 4; ++nf) {
            int ml = wr * 64 + mf * 16 + lg * 4;
            int nl = wc * 64 + nf * 16 + lr;
            f32x4 c = acc[mf][nf];
            sm.T[ml + 0][nl] = f2bf(c.x);
            sm.T[ml + 1][nl] = f2bf(c.y);
            sm.T[ml + 2][nl] = f2bf(c.z);
            sm.T[ml + 3][nl] = f2bf(c.w);
        }
    __syncthreads();
    {
        const int srow = tid >> 1, shalf = tid & 1;
        const int gm = m0 + srow;
        if (gm < 1360) {
            u16* drow = Z + (size_t)bz * 1360 * 4096 + (size_t)gm * 4096 + n0 + shalf * 64;
#pragma unroll
            for (int k = 0; k < 8; ++k)
                ((uint4*)drow)[k] = ((const uint4*)&sm.T[srow][shalf * 64])[k];
        }
    }
}

// ===================== spatial-major depthwise 3x3 + exact GELU: t[b][680][4096] =====================
__global__ __launch_bounds__(256) void dwgelu_kernel(
    const u16* __restrict__ z, const float* __restrict__ wdw, u16* __restrict__ t)
{
    __shared__ u16 zt[2][18][66];
    const int bz = blockIdx.z;
    const int c  = blockIdx.x;
    const int r0 = blockIdx.y * 16;
    const int tid = threadIdx.x;
    const u16* Z = z + (size_t)bz * 1360 * 4096;

#pragma unroll
    for (int sel = 0; sel < 2; ++sel) {
        const u16* src = Z + (size_t)(c + sel * 680) * 4096;
        for (int i = tid; i < 18 * 66; i += 256) {
            int rr = i / 66, cc = i % 66;
            int h = r0 - 1 + rr, w = cc - 1;
            u16 v = 0;
            if (h >= 0 && h < 64 && w >= 0 && w < 64) v = src[h * 64 + w];
            zt[sel][rr][cc] = v;
        }
    }
    __syncthreads();

    float w1r[9], w2r[9];
#pragma unroll
    for (int j = 0; j < 9; ++j) {
        w1r[j] = wdw[c * 9 + j];
        w2r[j] = wdw[(c + 680) * 9 + j];
    }
    const int hl = tid >> 4;
    const int w0 = (tid & 15) * 4;

    float d1a[4] = {0.f, 0.f, 0.f, 0.f}, d2a[4] = {0.f, 0.f, 0.f, 0.f};
#pragma unroll
    for (int dy = 0; dy < 3; ++dy) {
        float r1[6], r2[6];
#pragma unroll
        for (int k = 0; k < 6; ++k) {
            r1[k] = bf2f(zt[0][hl + dy][w0 + k]);
            r2[k] = bf2f(zt[1][hl + dy][w0 + k]);
        }
#pragma unroll
        for (int p = 0; p < 4; ++p) {
            d1a[p] += r1[p] * w1r[dy * 3] + r1[p + 1] * w1r[dy * 3 + 1] + r1[p + 2] * w1r[dy * 3 + 2];
            d2a[p] += r2[p] * w2r[dy * 3] + r2[p + 1] * w2r[dy * 3 + 1] + r2[p + 2] * w2r[dy * 3 + 2];
        }
    }
    unsigned pk[2];
#pragma unroll
    for (int k = 0; k < 2; ++k) {
        float da = d1a[k * 2], db = d1a[k * 2 + 1];
        float g0 = 0.5f * da * (1.f + erff(da * 0.70710678118654752f)) * d2a[k * 2];
        float g1 = 0.5f * db * (1.f + erff(db * 0.70710678118654752f)) * d2a[k * 2 + 1];
        pk[k] = (unsigned)f2bf(g0) | ((unsigned)f2bf(g1) << 16);
    }
    u16* dst = t + (size_t)bz * 680 * 4096 + (size_t)c * 4096 + (r0 + hl) * 64 + w0;
    *(uint2*)dst = make_uint2(pk[0], pk[1]);
}

// ===================== transpose: t[b][680][4096] -> tT[b][4096][704] (zero-padded K) =====================
// grid (64, 11, nb), block 256. 11*64 = 704 covers padded column range.
__global__ __launch_bounds__(256) void transpose_kernel(
    const u16* __restrict__ t, u16* __restrict__ tT)
{
    __shared__ u16 tile[64][68];
    const int bz = blockIdx.z;
    const int p0 = blockIdx.x * 64;
    const int c0 = blockIdx.y * 64;
    const int tid = threadIdx.x;
    const u16* src = t + (size_t)bz * 680 * 4096;
    u16* dst = tT + (size_t)bz * 4096 * 704;

#pragma unroll
    for (int it = 0; it < 4; ++it) {
        int i = tid + it * 256;
        int r = i >> 4, cc = (i & 15) * 4;
        uint2 v = make_uint2(0u, 0u);
        if (c0 + r < 680) v = *(const uint2*)&src[(size_t)(c0 + r) * 4096 + p0 + cc];
        *(uint2*)&tile[r][cc] = v;
    }
    __syncthreads();
#pragma unroll
    for (int it = 0; it < 4; ++it) {
        int i = tid + it * 256;
        int pp = i >> 4, cc = (i & 15) * 4;
        u16 a = tile[cc][pp], b = tile[cc + 1][pp];
        u16 c = tile[cc + 2][pp], d = tile[cc + 3][pp];
        uint2 v;
        v.x = (unsigned)a | ((unsigned)b << 16);
        v.y = (unsigned)c | ((unsigned)d << 16);
        *(uint2*)&dst[(size_t)(p0 + pp) * 704 + c0 + cc] = v;   // pad cols get zeros
    }
}

// ===================== MFMA GEMM2: out[b][256][4096] += w_out . t  (K padded to 704) =====================
// grid 64*nb (1D, XCD-chunked), block 256, 128x128 tile, BK=64, 11 clean K-steps.
__global__ __launch_bounds__(256, 2) void gemm2_kernel(
    const u16* __restrict__ Abf, const u16* __restrict__ Bt, float* __restrict__ out)
{
    __shared__ u16 As[128][64];
    __shared__ u16 Bs[128][64];

    const int bid = blockIdx.x;
    const int cpx = gridDim.x >> 3;
    const int W = (bid & 7) * cpx + (bid >> 3);
    const int bz = W >> 6;
    const int rem = W & 63;
    const int nb = rem >> 1, mb = rem & 1;
    const int m0 = mb * 128, n0 = nb * 128;

    const int tid = threadIdx.x;
    const int w = tid >> 6, l = tid & 63;
    const int wr = w >> 1, wc = w & 1;
    const int lr = l & 15, lg = l >> 4;
    const int lr8 = l >> 3, lc8 = l & 7;
    const int csw = (lc8 ^ lr8) * 8;

    f32x4 acc[4][4];
    const f32x4 fzero = {0.f, 0.f, 0.f, 0.f};
#pragma unroll
    for (int i = 0; i < 4; ++i)
#pragma unroll
        for (int j = 0; j < 4; ++j) acc[i][j] = fzero;

#pragma unroll 1
    for (int kt = 0; kt < 11; ++kt) {
        __syncthreads();
        const int kOff = kt * 64;
#pragma unroll
        for (int i = 0; i < 4; ++i) {
            const int j = w * 4 + i;
            gload16(Abf + (size_t)(m0 + j * 8 + lr8) * 704 + kOff + csw, &As[j * 8][0]);
            gload16(Bt + ((size_t)bz * 4096 + n0 + j * 8 + lr8) * 704 + kOff + csw,
                    &Bs[j * 8][0]);
        }
        __syncthreads();
#pragma unroll
        for (int kc = 0; kc < 2; ++kc) {
            bf16x8 af[4], bfr[4];
#pragma unroll
            for (int mf = 0; mf < 4; ++mf) {
                const int R = wr * 64 + mf * 16 + lr;
                af[mf] = *(const bf16x8*)&As[R][(((kc << 2) | lg) ^ (R & 7)) << 3];
            }
#pragma unroll
            for (int nf = 0; nf < 4; ++nf) {
                const int R = wc * 64 + nf * 16 + lr;
                bfr[nf] = *(const bf16x8*)&Bs[R][(((kc << 2) | lg) ^ (R & 7)) << 3];
            }
#pragma unroll
            for (int mf = 0; mf < 4; ++mf)
#pragma unroll
                for (int nf = 0; nf < 4; ++nf)
                    acc[mf][nf] = __builtin_amdgcn_mfma_f32_16x16x32_bf16(af[mf], bfr[nf], acc[mf][nf], 0, 0, 0);
        }
    }
#pragma unroll
    for (int mf = 0; mf < 4; ++mf)
#pragma unroll
        for (int nf = 0; nf < 4; ++nf) {
            int m = m0 + wr * 64 + mf * 16 + lg * 4;
            int n = n0 + wc * 64 + nf * 16 + lr;
            size_t base = ((size_t)bz * 256 + m) * 4096 + n;
            f32x4 c = acc[mf][nf];
#pragma unroll
            for (int r = 0; r < 4; ++r) {
                size_t idx = base + (size_t)r * 4096;
                out[idx] = out[idx] + c[r];
            }
        }
}

// ===================== host =====================
extern "C" void kernel_launch(void* const* d_in, const int* in_sizes, int n_in,
                              void* d_out, int out_size, void* d_ws, size_t ws_size,
                              hipStream_t stream)
{
    const float* x     = (const float*)d_in[0];
    const float* ln1w  = (const float*)d_in[1];
    const float* ln1b  = (const float*)d_in[2];
    const float* w1    = (const float*)d_in[3];
    const float* b1    = (const float*)d_in[4];
    const float* w3    = (const float*)d_in[5];
    const float* b3    = (const float*)d_in[6];
    const float* gnw   = (const float*)d_in[7];
    const float* gnb   = (const float*)d_in[8];
    const float* ln2w  = (const float*)d_in[9];
    const float* ln2b  = (const float*)d_in[10];
    const float* w_in  = (const float*)d_in[11];
    const float* w_dw  = (const float*)d_in[12];
    const float* w_out = (const float*)d_in[13];
    float* out = (float*)d_out;

    char* ws = (char*)d_ws;
    const size_t OFF_RS  = 131072;
    const size_t OFF_Y2T = 262144;
    const size_t OFF_WIB = 17039360;        // y2T end
    const size_t OFF_WOB = 17735680;        // wib end; wob = 256*704*2 = 360448
    const size_t OFF_Z   = 18096128;        // wob end
    const size_t Z_FULL  = 89128960;        // 8*1360*4096*2
    const size_t OFF_T   = OFF_Z + Z_FULL;  // 107225088
    const size_t T_FULL  = 44564480;        // 8*680*4096*2
    const size_t NEED_FULL = OFF_T + T_FULL; // 151789568
    // tT (8*4096*704*2 = 46137344) overlays z, which is dead after dwgelu.

    float* mu_g = (float*)(ws);
    float* rs_g = (float*)(ws + OFF_RS);
    u16*   y2T  = (u16*)(ws + OFF_Y2T);
    u16*   wib  = (u16*)(ws + OFF_WIB);
    u16*   wob  = (u16*)(ws + OFF_WOB);
    const bool full = ws_size >= NEED_FULL;

    prep_kernel<<<dim3(1360), dim3(256), 0, stream>>>(w_in, w_out, wib, wob);
    ln_stats_kernel<<<dim3(64, 8), dim3(256), 0, stream>>>(x, mu_g, rs_g);
    attn_kernel<<<dim3(64, 8), dim3(1024), 0, stream>>>(x, mu_g, rs_g, ln1w, ln1b,
                                                        w1, b1, w3, b3, gnw, gnb, out);
    ln2T_kernel<<<dim3(128, 8), dim3(256), 0, stream>>>(out, ln2w, ln2b, y2T);

    if (full) {
        u16* z   = (u16*)(ws + OFF_Z);
        u16* t   = (u16*)(ws + OFF_T);
        u16* tT  = (u16*)(ws + OFF_Z);
        gemm1_kernel<<<dim3(352 * 8), dim3(256), 0, stream>>>(wib, y2T, z);
        dwgelu_kernel<<<dim3(680, 4, 8), dim3(256), 0, stream>>>(z, w_dw, t);
        transpose_kernel<<<dim3(64, 11, 8), dim3(256), 0, stream>>>(t, tT);
        gemm2_kernel<<<dim3(64 * 8), dim3(256), 0, stream>>>(wob, tT, out);
    } else {
        const size_t Z1  = (size_t)1360 * 4096 * 2;   // 11141120
        const size_t T1  = (size_t)680 * 4096 * 2;    // 5570560
        u16* z  = (u16*)(ws + OFF_Z);
        u16* t  = (u16*)(ws + OFF_Z + Z1);
        u16* tT = (u16*)(ws + OFF_Z + Z1 + T1);
        for (int b = 0; b < 8; ++b) {
            gemm1_kernel<<<dim3(352), dim3(256), 0, stream>>>(
                wib, y2T + (size_t)b * 4096 * 256, z);
            dwgelu_kernel<<<dim3(680, 4, 1), dim3(256), 0, stream>>>(z, w_dw, t);
            transpose_kernel<<<dim3(64, 11, 1), dim3(256), 0, stream>>>(t, tT);
            gemm2_kernel<<<dim3(64), dim3(256), 0, stream>>>(
                wob, tT, out + (size_t)b * 256 * 4096);
        }
    }
}